// Round 3
// baseline (600.990 us; speedup 1.0000x reference)
//
#include <hip/hip_runtime.h>
#include <stdint.h>

typedef unsigned short u16;
typedef unsigned int   u32;
typedef __bf16 bf16_t;
typedef bf16_t bf16x4 __attribute__((ext_vector_type(4)));
typedef bf16_t bf16x8 __attribute__((ext_vector_type(8)));
typedef float  f32x4  __attribute__((ext_vector_type(4)));
typedef u16    u16x8  __attribute__((ext_vector_type(8)));

#define BB 2
#define NN 2048
#define CC 2048
#define HH 16
#define DD 128
#define FF 6144
#define MM 4096

__device__ __forceinline__ u16 f2bf(float f){
    u32 u = __builtin_bit_cast(u32, f);
    u32 r = (u + 0x7fffu + ((u >> 16) & 1u)) >> 16;
    return (u16)r;
}
__device__ __forceinline__ float bf2f(u16 h){
    u32 u = ((u32)h) << 16;
    return __builtin_bit_cast(float, u);
}
__device__ __forceinline__ f32x4 MFMA(bf16x8 a, bf16x8 b, f32x4 c){
    return __builtin_amdgcn_mfma_f32_16x16x32_bf16(a, b, c, 0, 0, 0);
}
__device__ __forceinline__ void gld16(const void* g, void* l){
    __builtin_amdgcn_global_load_lds(
        (const __attribute__((address_space(1))) void*)(g),
        (__attribute__((address_space(3))) void*)(l), 16, 0, 0);
}

// ---------------- conversion kernels ----------------
__global__ void k_split_x(const float* __restrict__ x, u16* __restrict__ xhi,
                          u16* __restrict__ xlo, int n4){
    int i = blockIdx.x * blockDim.x + threadIdx.x;
    int stride = gridDim.x * blockDim.x;
    for (; i < n4; i += stride){
        float4 v = ((const float4*)x)[i];
        u16 h0 = f2bf(v.x), h1 = f2bf(v.y), h2 = f2bf(v.z), h3 = f2bf(v.w);
        ushort4 hi; hi.x = h0; hi.y = h1; hi.z = h2; hi.w = h3;
        ushort4 lo;
        lo.x = f2bf(v.x - bf2f(h0));
        lo.y = f2bf(v.y - bf2f(h1));
        lo.z = f2bf(v.z - bf2f(h2));
        lo.w = f2bf(v.w - bf2f(h3));
        ((ushort4*)xhi)[i] = hi;
        ((ushort4*)xlo)[i] = lo;
    }
}

__global__ void k_f2bf(const float* __restrict__ a, u16* __restrict__ o, int n4){
    int i = blockIdx.x * blockDim.x + threadIdx.x;
    int stride = gridDim.x * blockDim.x;
    for (; i < n4; i += stride){
        float4 v = ((const float4*)a)[i];
        ushort4 r; r.x = f2bf(v.x); r.y = f2bf(v.y); r.z = f2bf(v.z); r.w = f2bf(v.w);
        ((ushort4*)o)[i] = r;
    }
}

// ---------------- GEMM:  out[m][n] = sum_k A[m][k] * Bw[n][k]  ----------------
// SPLIT: A2 (low-order bf16 of A) staged in the SAME phase -> 32 MFMA per barrier pair
template<int SPLIT, int OUTBF>
__global__ __launch_bounds__(256) void k_gemm_bt(
    const u16* __restrict__ A, const u16* __restrict__ A2,
    const u16* __restrict__ Bw, float* __restrict__ outf, u16* __restrict__ outb,
    const float* __restrict__ bias, int M, int N, int K)
{
    __shared__ u16 As [128 * 32];
    __shared__ u16 Bs [128 * 32];
    __shared__ u16 A2s[SPLIT ? 128 * 32 : 64];
    const int tid  = threadIdx.x;
    const int brow = blockIdx.y * 128;
    const int bcol = blockIdx.x * 128;
    const int w = tid >> 6, lane = tid & 63;
    const int wr = w >> 1, wc = w & 1;
    const int l15 = lane & 15, g = lane >> 4;
    const int sr = tid >> 2;            // 0..63
    const int sc_ = (tid & 3) * 8;      // 0,8,16,24

    f32x4 acc[4][4];
    #pragma unroll
    for (int i = 0; i < 4; i++)
        #pragma unroll
        for (int j = 0; j < 4; j++){
            f32x4 z = {0.f, 0.f, 0.f, 0.f};
            acc[i][j] = z;
        }

    for (int k0 = 0; k0 < K; k0 += 32){
        __syncthreads();
        gld16(&Bw[(size_t)(bcol + sr) * K + k0 + sc_],      &Bs[w * 512]);
        gld16(&Bw[(size_t)(bcol + sr + 64) * K + k0 + sc_], &Bs[2048 + w * 512]);
        gld16(&A [(size_t)(brow + sr) * K + k0 + sc_],      &As[w * 512]);
        gld16(&A [(size_t)(brow + sr + 64) * K + k0 + sc_], &As[2048 + w * 512]);
        if (SPLIT){
            gld16(&A2[(size_t)(brow + sr) * K + k0 + sc_],      &A2s[w * 512]);
            gld16(&A2[(size_t)(brow + sr + 64) * K + k0 + sc_], &A2s[2048 + w * 512]);
        }
        __syncthreads();
        bf16x8 fb[4];
        #pragma unroll
        for (int j = 0; j < 4; j++){
            int row = wc * 64 + j * 16 + l15;
            fb[j] = *(const bf16x8*)&Bs[row * 32 + 8 * g];
        }
        #pragma unroll
        for (int i = 0; i < 4; i++){
            int row = wr * 64 + i * 16 + l15;
            bf16x8 fa = *(const bf16x8*)&As[row * 32 + 8 * g];
            #pragma unroll
            for (int j = 0; j < 4; j++) acc[i][j] = MFMA(fa, fb[j], acc[i][j]);
            if (SPLIT){
                bf16x8 fa2 = *(const bf16x8*)&A2s[row * 32 + 8 * g];
                #pragma unroll
                for (int j = 0; j < 4; j++) acc[i][j] = MFMA(fa2, fb[j], acc[i][j]);
            }
        }
    }

    #pragma unroll
    for (int i = 0; i < 4; i++){
        #pragma unroll
        for (int j = 0; j < 4; j++){
            int colg = bcol + wc * 64 + j * 16 + l15;
            #pragma unroll
            for (int r = 0; r < 4; r++){
                int rowg = brow + wr * 64 + i * 16 + 4 * g + r;
                float v = acc[i][j][r];
                if (OUTBF) outb[(size_t)rowg * N + colg] = f2bf(v);
                else       outf[(size_t)rowg * N + colg] = v + bias[colg];
            }
        }
    }
}

// ---------------- RMSNorm + RoPE + transpose to (B,H,N,D) ----------------
__global__ __launch_bounds__(256) void k_norm_rope(
    const u16* __restrict__ qkv, const float* __restrict__ qw, const float* __restrict__ kw,
    const float* __restrict__ cosb, const float* __restrict__ sinb,
    u16* __restrict__ qout, u16* __restrict__ kout, u16* __restrict__ vout)
{
    const int m = blockIdx.x;           // 0..4095  (b*N + n)
    const int b = m >> 11;
    const int n = m & 2047;
    const int t = threadIdx.x;
    const size_t base = (size_t)m * FF;
    const int e0 = t * 8;

    float qv[8], kvv[8];
    uint4 qa = *(const uint4*)&qkv[base + e0];
    uint4 ka = *(const uint4*)&qkv[base + CC + e0];
    uint4 va = *(const uint4*)&qkv[base + 2 * CC + e0];
    {
        u32 aa[4] = {qa.x, qa.y, qa.z, qa.w};
        u32 bb[4] = {ka.x, ka.y, ka.z, ka.w};
        #pragma unroll
        for (int i = 0; i < 4; i++){
            qv[2*i]   = bf2f((u16)(aa[i] & 0xffff));
            qv[2*i+1] = bf2f((u16)(aa[i] >> 16));
            kvv[2*i]   = bf2f((u16)(bb[i] & 0xffff));
            kvv[2*i+1] = bf2f((u16)(bb[i] >> 16));
        }
    }
    float sq = 0.f, sk = 0.f;
    #pragma unroll
    for (int i = 0; i < 8; i++){ sq += qv[i]*qv[i]; sk += kvv[i]*kvv[i]; }
    #pragma unroll
    for (int o = 32; o > 0; o >>= 1){ sq += __shfl_xor(sq, o); sk += __shfl_xor(sk, o); }
    __shared__ float red[8];
    if ((t & 63) == 0){ red[(t >> 6)*2] = sq; red[(t >> 6)*2 + 1] = sk; }
    __syncthreads();
    sq = red[0] + red[2] + red[4] + red[6];
    sk = red[1] + red[3] + red[5] + red[7];
    const float rq = rsqrtf(sq * (1.f / 2048.f) + 1e-5f);
    const float rk = rsqrtf(sk * (1.f / 2048.f) + 1e-5f);

    const int h  = t >> 4;
    const int d0 = (t & 15) * 8;
    const float* cp = cosb + (size_t)n * DD + d0;
    const float* sp = sinb + (size_t)n * DD + d0;
    float qo[8], ko[8];
    #pragma unroll
    for (int j = 0; j < 8; j += 2){
        float c0 = cp[j], c1 = cp[j+1], s0 = sp[j], s1 = sp[j+1];
        float x0 = qv[j]   * rq * qw[e0 + j];
        float x1 = qv[j+1] * rq * qw[e0 + j + 1];
        qo[j]   = x0 * c0 - x1 * s0;
        qo[j+1] = x1 * c1 + x0 * s1;
        float y0 = kvv[j]   * rk * kw[e0 + j];
        float y1 = kvv[j+1] * rk * kw[e0 + j + 1];
        ko[j]   = y0 * c0 - y1 * s0;
        ko[j+1] = y1 * c1 + y0 * s1;
    }
    const size_t obase = ((size_t)(b * HH + h) * NN + n) * DD + d0;
    uint4 pq, pk;
    pq.x = (u32)f2bf(qo[0]) | ((u32)f2bf(qo[1]) << 16);
    pq.y = (u32)f2bf(qo[2]) | ((u32)f2bf(qo[3]) << 16);
    pq.z = (u32)f2bf(qo[4]) | ((u32)f2bf(qo[5]) << 16);
    pq.w = (u32)f2bf(qo[6]) | ((u32)f2bf(qo[7]) << 16);
    pk.x = (u32)f2bf(ko[0]) | ((u32)f2bf(ko[1]) << 16);
    pk.y = (u32)f2bf(ko[2]) | ((u32)f2bf(ko[3]) << 16);
    pk.z = (u32)f2bf(ko[4]) | ((u32)f2bf(ko[5]) << 16);
    pk.w = (u32)f2bf(ko[6]) | ((u32)f2bf(ko[7]) << 16);
    *(uint4*)&qout[obase] = pq;
    *(uint4*)&kout[obase] = pk;
    *(uint4*)&vout[obase] = va;   // v: pass-through (already bf16)
}

// ---------------- V transpose: (BH, N, D) -> (BH, D, N) ----------------
__global__ __launch_bounds__(256) void k_vtrans(const u16* __restrict__ V, u16* __restrict__ Vt){
    __shared__ u16 t[64 * 66];
    const int bh = blockIdx.z;
    const int n0 = blockIdx.x * 64, d0 = blockIdx.y * 64;
    const int tid = threadIdx.x;
    const int q = tid & 7, p = tid >> 3;
    #pragma unroll
    for (int it = 0; it < 2; it++){
        int r = p + it * 32;
        const u16* src = V + ((size_t)bh * NN + n0 + r) * DD + d0 + q * 8;
        uint4 v = *(const uint4*)src;
        u32* dst = (u32*)&t[r * 66 + q * 8];
        dst[0] = v.x; dst[1] = v.y; dst[2] = v.z; dst[3] = v.w;
    }
    __syncthreads();
    #pragma unroll
    for (int it = 0; it < 2; it++){
        int rd = p + it * 32;
        u16 o[8];
        #pragma unroll
        for (int j = 0; j < 8; j++) o[j] = t[(q * 8 + j) * 66 + rd];
        *(uint4*)(Vt + ((size_t)bh * DD + d0 + rd) * NN + n0 + q * 8) = *(uint4*)o;
    }
}

// ---------------- attention v3: kv-split 2 waves/block + cross-wave LDS reduce ----------------
__global__ __launch_bounds__(128, 4) void k_attn3(
    const u16* __restrict__ Q, const u16* __restrict__ Kt, const u16* __restrict__ Vt2,
    u16* __restrict__ O)
{
    const int w = threadIdx.x >> 6, lane = threadIdx.x & 63;
    const int l15 = lane & 15, g = lane >> 4;
    // bijective XCD swizzle: 2048 blocks, each XCD gets 256 contiguous logical ids
    const int flat = blockIdx.x;
    const int lid  = (flat & 7) * 256 + (flat >> 3);
    const int qt = lid & 63;            // 64 q-tiles of 32 rows
    const int h  = (lid >> 6) & 15;
    const int b  = lid >> 10;
    const size_t hb  = (size_t)(b * HH + h) * NN * DD;  // Q, K: (N,D)
    const size_t hbT = (size_t)(b * HH + h) * DD * NN;  // Vt2: (D,N)
    const int qbase = qt * 32;
    const float sc = 0.08838834764831845f * 1.4426950408889634f; // D^-0.5 * log2(e)

    bf16x8 qf[2][4];
    #pragma unroll
    for (int u = 0; u < 2; u++){
        const u16* qrow = Q + hb + (size_t)(qbase + u * 16 + l15) * DD;
        #pragma unroll
        for (int c = 0; c < 4; c++)
            qf[u][c] = *(const bf16x8*)(qrow + c * 32 + 8 * g);
    }

    f32x4 oacc[2][8];
    #pragma unroll
    for (int u = 0; u < 2; u++)
        #pragma unroll
        for (int tb = 0; tb < 8; tb++){ f32x4 z = {0.f,0.f,0.f,0.f}; oacc[u][tb] = z; }
    float lsum0 = 0.f, lsum1 = 0.f;

    const int mperm = 8 * (l15 >> 2) + (l15 & 3);

    // wave w handles kv tiles {32w, 32w+64, ...}
    for (int kv0 = w * 32; kv0 < NN; kv0 += 64){
        const u16* k0row = Kt + hb + (size_t)(kv0 + mperm) * DD;
        const u16* k1row = k0row + 4 * DD;
        f32x4 st00 = {0,0,0,0}, st01 = {0,0,0,0}, st10 = {0,0,0,0}, st11 = {0,0,0,0};
        #pragma unroll
        for (int c = 0; c < 4; c++){
            bf16x8 kf0 = *(const bf16x8*)(k0row + c * 32 + 8 * g);
            bf16x8 kf1 = *(const bf16x8*)(k1row + c * 32 + 8 * g);
            st00 = MFMA(kf0, qf[0][c], st00);
            st01 = MFMA(kf0, qf[1][c], st01);
            st10 = MFMA(kf1, qf[0][c], st10);
            st11 = MFMA(kf1, qf[1][c], st11);
        }
        u16x8 pu0, pu1;
        #pragma unroll
        for (int r = 0; r < 4; r++){
            u16 a0 = f2bf(exp2f(st00[r] * sc));
            u16 a1 = f2bf(exp2f(st10[r] * sc));
            pu0[r] = a0; pu0[r + 4] = a1;
            lsum0 += bf2f(a0) + bf2f(a1);
            u16 b0 = f2bf(exp2f(st01[r] * sc));
            u16 b1 = f2bf(exp2f(st11[r] * sc));
            pu1[r] = b0; pu1[r + 4] = b1;
            lsum1 += bf2f(b0) + bf2f(b1);
        }
        bf16x8 pf0 = __builtin_bit_cast(bf16x8, pu0);
        bf16x8 pf1 = __builtin_bit_cast(bf16x8, pu1);
        #pragma unroll
        for (int tb = 0; tb < 8; tb++){
            bf16x8 vf = *(const bf16x8*)(Vt2 + hbT + (size_t)(tb * 16 + l15) * NN + kv0 + 8 * g);
            oacc[0][tb] = MFMA(pf0, vf, oacc[0][tb]);
            oacc[1][tb] = MFMA(pf1, vf, oacc[1][tb]);
        }
    }

    // ---- cross-wave reduction: wave1 -> LDS, wave0 accumulates ----
    __shared__ float red[64 * 64 + 128];
    if (w == 1){
        #pragma unroll
        for (int u = 0; u < 2; u++)
            #pragma unroll
            for (int tb = 0; tb < 8; tb++)
                #pragma unroll
                for (int r = 0; r < 4; r++)
                    red[((u * 8 + tb) * 4 + r) * 64 + lane] = oacc[u][tb][r];
        red[4096 + lane]      = lsum0;
        red[4096 + 64 + lane] = lsum1;
    }
    __syncthreads();
    if (w == 0){
        #pragma unroll
        for (int u = 0; u < 2; u++)
            #pragma unroll
            for (int tb = 0; tb < 8; tb++)
                #pragma unroll
                for (int r = 0; r < 4; r++)
                    oacc[u][tb][r] += red[((u * 8 + tb) * 4 + r) * 64 + lane];
        lsum0 += red[4096 + lane];
        lsum1 += red[4096 + 64 + lane];

        lsum0 += __shfl_xor(lsum0, 16); lsum0 += __shfl_xor(lsum0, 32);
        lsum1 += __shfl_xor(lsum1, 16); lsum1 += __shfl_xor(lsum1, 32);
        float linv0 = 1.f / lsum0, linv1 = 1.f / lsum1;
        float li0[4], li1[4];
        #pragma unroll
        for (int r = 0; r < 4; r++){
            li0[r] = __shfl(linv0, 4 * g + r);
            li1[r] = __shfl(linv1, 4 * g + r);
        }

        #pragma unroll
        for (int tb = 0; tb < 8; tb++){
            #pragma unroll
            for (int r = 0; r < 4; r++){
                int q0 = qbase + 4 * g + r;
                O[(size_t)(b * NN + q0) * CC + h * DD + tb * 16 + l15] = f2bf(oacc[0][tb][r] * li0[r]);
                int q1 = qbase + 16 + 4 * g + r;
                O[(size_t)(b * NN + q1) * CC + h * DD + tb * 16 + l15] = f2bf(oacc[1][tb][r] * li1[r]);
            }
        }
    }
}

// ---------------- launch ----------------
extern "C" void kernel_launch(void* const* d_in, const int* in_sizes, int n_in,
                              void* d_out, int out_size, void* d_ws, size_t ws_size,
                              hipStream_t stream) {
    const float* x      = (const float*)d_in[0];
    const float* w_qkv  = (const float*)d_in[1];
    const float* qw     = (const float*)d_in[2];
    const float* kw     = (const float*)d_in[3];
    const float* cosb   = (const float*)d_in[4];
    const float* sinb   = (const float*)d_in[5];
    const float* w_proj = (const float*)d_in[6];
    const float* b_proj = (const float*)d_in[7];
    float* out = (float*)d_out;

    const size_t sz_xhi  = (size_t)MM * CC * 2;        // 16 MiB
    const size_t sz_wqkv = (size_t)FF * CC * 2;        // 24 MiB
    const size_t sz_wprj = (size_t)CC * CC * 2;        // 8 MiB
    const size_t sz_qkv  = (size_t)MM * FF * 2;        // 48 MiB
    const size_t sz_t    = (size_t)BB * HH * NN * DD * 2; // 16 MiB each
    const size_t need = sz_xhi*2 + sz_wqkv + sz_wprj + sz_qkv + sz_t*3 + sz_xhi;
    if (ws_size < need) return;

    char* ws = (char*)d_ws;
    size_t off = 0;
    auto alloc = [&](size_t bytes){ void* p = ws + off; off += (bytes + 255) & ~(size_t)255; return p; };
    u16* x_hi    = (u16*)alloc(sz_xhi);
    u16* x_lo    = (u16*)alloc(sz_xhi);
    u16* wqkv_bf = (u16*)alloc(sz_wqkv);
    u16* wprj_bf = (u16*)alloc(sz_wprj);
    u16* qkv     = (u16*)alloc(sz_qkv);
    u16* qr      = (u16*)alloc(sz_t);
    u16* kr      = (u16*)alloc(sz_t);
    u16* vt      = (u16*)alloc(sz_t);
    u16* ob      = (u16*)alloc(sz_xhi);
    u16* vt2     = qkv;   // qkv is dead after k_norm_rope; reuse for transposed V

    k_split_x<<<2048, 256, 0, stream>>>(x, x_hi, x_lo, MM * CC / 4);
    k_f2bf<<<2048, 256, 0, stream>>>(w_qkv, wqkv_bf, FF * CC / 4);
    k_f2bf<<<1024, 256, 0, stream>>>(w_proj, wprj_bf, CC * CC / 4);
    k_gemm_bt<1, 1><<<dim3(FF / 128, MM / 128), 256, 0, stream>>>(
        x_hi, x_lo, wqkv_bf, nullptr, qkv, nullptr, MM, FF, CC);
    k_norm_rope<<<MM, 256, 0, stream>>>(qkv, qw, kw, cosb, sinb, qr, kr, vt);
    k_vtrans<<<dim3(NN / 64, DD / 64, BB * HH), 256, 0, stream>>>(vt, vt2);
    k_attn3<<<2048, 128, 0, stream>>>(qr, kr, vt2, ob);
    k_gemm_bt<0, 0><<<dim3(CC / 128, MM / 128), 256, 0, stream>>>(
        ob, nullptr, wprj_bf, out, nullptr, b_proj, MM, CC, CC);
}

// Round 4
// 539.736 us; speedup vs baseline: 1.1135x; 1.1135x over previous
//
#include <hip/hip_runtime.h>
#include <stdint.h>

typedef unsigned short u16;
typedef unsigned int   u32;
typedef __bf16 bf16_t;
typedef bf16_t bf16x4 __attribute__((ext_vector_type(4)));
typedef bf16_t bf16x8 __attribute__((ext_vector_type(8)));
typedef float  f32x4  __attribute__((ext_vector_type(4)));
typedef u16    u16x8  __attribute__((ext_vector_type(8)));

#define BB 2
#define NN 2048
#define CC 2048
#define HH 16
#define DD 128
#define FF 6144
#define MM 4096

__device__ __forceinline__ u16 f2bf(float f){
    u32 u = __builtin_bit_cast(u32, f);
    u32 r = (u + 0x7fffu + ((u >> 16) & 1u)) >> 16;
    return (u16)r;
}
__device__ __forceinline__ float bf2f(u16 h){
    u32 u = ((u32)h) << 16;
    return __builtin_bit_cast(float, u);
}
__device__ __forceinline__ f32x4 MFMA(bf16x8 a, bf16x8 b, f32x4 c){
    return __builtin_amdgcn_mfma_f32_16x16x32_bf16(a, b, c, 0, 0, 0);
}
__device__ __forceinline__ void gld16(const void* g, void* l){
    __builtin_amdgcn_global_load_lds(
        (const __attribute__((address_space(1))) void*)(g),
        (__attribute__((address_space(3))) void*)(l), 16, 0, 0);
}

// ---------------- conversion kernels ----------------
__global__ void k_split_x(const float* __restrict__ x, u16* __restrict__ xhi,
                          u16* __restrict__ xlo, int n4){
    int i = blockIdx.x * blockDim.x + threadIdx.x;
    int stride = gridDim.x * blockDim.x;
    for (; i < n4; i += stride){
        float4 v = ((const float4*)x)[i];
        u16 h0 = f2bf(v.x), h1 = f2bf(v.y), h2 = f2bf(v.z), h3 = f2bf(v.w);
        ushort4 hi; hi.x = h0; hi.y = h1; hi.z = h2; hi.w = h3;
        ushort4 lo;
        lo.x = f2bf(v.x - bf2f(h0));
        lo.y = f2bf(v.y - bf2f(h1));
        lo.z = f2bf(v.z - bf2f(h2));
        lo.w = f2bf(v.w - bf2f(h3));
        ((ushort4*)xhi)[i] = hi;
        ((ushort4*)xlo)[i] = lo;
    }
}

__global__ void k_f2bf(const float* __restrict__ a, u16* __restrict__ o, int n4){
    int i = blockIdx.x * blockDim.x + threadIdx.x;
    int stride = gridDim.x * blockDim.x;
    for (; i < n4; i += stride){
        float4 v = ((const float4*)a)[i];
        ushort4 r; r.x = f2bf(v.x); r.y = f2bf(v.y); r.z = f2bf(v.z); r.w = f2bf(v.w);
        ((ushort4*)o)[i] = r;
    }
}

// ---------------- GEMM:  out[m][n] = sum_k A[m][k] * Bw[n][k]  ----------------
// SPLIT: A2 (low-order bf16 of A) staged in the SAME phase -> 32 MFMA per barrier pair
template<int SPLIT, int OUTBF>
__global__ __launch_bounds__(256) void k_gemm_bt(
    const u16* __restrict__ A, const u16* __restrict__ A2,
    const u16* __restrict__ Bw, float* __restrict__ outf, u16* __restrict__ outb,
    const float* __restrict__ bias, int M, int N, int K)
{
    __shared__ u16 As [128 * 32];
    __shared__ u16 Bs [128 * 32];
    __shared__ u16 A2s[SPLIT ? 128 * 32 : 64];
    const int tid  = threadIdx.x;
    const int brow = blockIdx.y * 128;
    const int bcol = blockIdx.x * 128;
    const int w = tid >> 6, lane = tid & 63;
    const int wr = w >> 1, wc = w & 1;
    const int l15 = lane & 15, g = lane >> 4;
    const int sr = tid >> 2;            // 0..63
    const int sc_ = (tid & 3) * 8;      // 0,8,16,24

    f32x4 acc[4][4];
    #pragma unroll
    for (int i = 0; i < 4; i++)
        #pragma unroll
        for (int j = 0; j < 4; j++){
            f32x4 z = {0.f, 0.f, 0.f, 0.f};
            acc[i][j] = z;
        }

    for (int k0 = 0; k0 < K; k0 += 32){
        __syncthreads();
        gld16(&Bw[(size_t)(bcol + sr) * K + k0 + sc_],      &Bs[w * 512]);
        gld16(&Bw[(size_t)(bcol + sr + 64) * K + k0 + sc_], &Bs[2048 + w * 512]);
        gld16(&A [(size_t)(brow + sr) * K + k0 + sc_],      &As[w * 512]);
        gld16(&A [(size_t)(brow + sr + 64) * K + k0 + sc_], &As[2048 + w * 512]);
        if (SPLIT){
            gld16(&A2[(size_t)(brow + sr) * K + k0 + sc_],      &A2s[w * 512]);
            gld16(&A2[(size_t)(brow + sr + 64) * K + k0 + sc_], &A2s[2048 + w * 512]);
        }
        __syncthreads();
        bf16x8 fb[4];
        #pragma unroll
        for (int j = 0; j < 4; j++){
            int row = wc * 64 + j * 16 + l15;
            fb[j] = *(const bf16x8*)&Bs[row * 32 + 8 * g];
        }
        #pragma unroll
        for (int i = 0; i < 4; i++){
            int row = wr * 64 + i * 16 + l15;
            bf16x8 fa = *(const bf16x8*)&As[row * 32 + 8 * g];
            #pragma unroll
            for (int j = 0; j < 4; j++) acc[i][j] = MFMA(fa, fb[j], acc[i][j]);
            if (SPLIT){
                bf16x8 fa2 = *(const bf16x8*)&A2s[row * 32 + 8 * g];
                #pragma unroll
                for (int j = 0; j < 4; j++) acc[i][j] = MFMA(fa2, fb[j], acc[i][j]);
            }
        }
    }

    #pragma unroll
    for (int i = 0; i < 4; i++){
        #pragma unroll
        for (int j = 0; j < 4; j++){
            int colg = bcol + wc * 64 + j * 16 + l15;
            #pragma unroll
            for (int r = 0; r < 4; r++){
                int rowg = brow + wr * 64 + i * 16 + 4 * g + r;
                float v = acc[i][j][r];
                if (OUTBF) outb[(size_t)rowg * N + colg] = f2bf(v);
                else       outf[(size_t)rowg * N + colg] = v + bias[colg];
            }
        }
    }
}

// ---------------- RMSNorm + RoPE + transpose to (B,H,N,D) ----------------
__global__ __launch_bounds__(256) void k_norm_rope(
    const u16* __restrict__ qkv, const float* __restrict__ qw, const float* __restrict__ kw,
    const float* __restrict__ cosb, const float* __restrict__ sinb,
    u16* __restrict__ qout, u16* __restrict__ kout, u16* __restrict__ vout)
{
    const int m = blockIdx.x;           // 0..4095  (b*N + n)
    const int b = m >> 11;
    const int n = m & 2047;
    const int t = threadIdx.x;
    const size_t base = (size_t)m * FF;
    const int e0 = t * 8;

    float qv[8], kvv[8];
    uint4 qa = *(const uint4*)&qkv[base + e0];
    uint4 ka = *(const uint4*)&qkv[base + CC + e0];
    uint4 va = *(const uint4*)&qkv[base + 2 * CC + e0];
    {
        u32 aa[4] = {qa.x, qa.y, qa.z, qa.w};
        u32 bb[4] = {ka.x, ka.y, ka.z, ka.w};
        #pragma unroll
        for (int i = 0; i < 4; i++){
            qv[2*i]   = bf2f((u16)(aa[i] & 0xffff));
            qv[2*i+1] = bf2f((u16)(aa[i] >> 16));
            kvv[2*i]   = bf2f((u16)(bb[i] & 0xffff));
            kvv[2*i+1] = bf2f((u16)(bb[i] >> 16));
        }
    }
    float sq = 0.f, sk = 0.f;
    #pragma unroll
    for (int i = 0; i < 8; i++){ sq += qv[i]*qv[i]; sk += kvv[i]*kvv[i]; }
    #pragma unroll
    for (int o = 32; o > 0; o >>= 1){ sq += __shfl_xor(sq, o); sk += __shfl_xor(sk, o); }
    __shared__ float red[8];
    if ((t & 63) == 0){ red[(t >> 6)*2] = sq; red[(t >> 6)*2 + 1] = sk; }
    __syncthreads();
    sq = red[0] + red[2] + red[4] + red[6];
    sk = red[1] + red[3] + red[5] + red[7];
    const float rq = rsqrtf(sq * (1.f / 2048.f) + 1e-5f);
    const float rk = rsqrtf(sk * (1.f / 2048.f) + 1e-5f);

    const int h  = t >> 4;
    const int d0 = (t & 15) * 8;
    const float* cp = cosb + (size_t)n * DD + d0;
    const float* sp = sinb + (size_t)n * DD + d0;
    float qo[8], ko[8];
    #pragma unroll
    for (int j = 0; j < 8; j += 2){
        float c0 = cp[j], c1 = cp[j+1], s0 = sp[j], s1 = sp[j+1];
        float x0 = qv[j]   * rq * qw[e0 + j];
        float x1 = qv[j+1] * rq * qw[e0 + j + 1];
        qo[j]   = x0 * c0 - x1 * s0;
        qo[j+1] = x1 * c1 + x0 * s1;
        float y0 = kvv[j]   * rk * kw[e0 + j];
        float y1 = kvv[j+1] * rk * kw[e0 + j + 1];
        ko[j]   = y0 * c0 - y1 * s0;
        ko[j+1] = y1 * c1 + y0 * s1;
    }
    const size_t obase = ((size_t)(b * HH + h) * NN + n) * DD + d0;
    uint4 pq, pk;
    pq.x = (u32)f2bf(qo[0]) | ((u32)f2bf(qo[1]) << 16);
    pq.y = (u32)f2bf(qo[2]) | ((u32)f2bf(qo[3]) << 16);
    pq.z = (u32)f2bf(qo[4]) | ((u32)f2bf(qo[5]) << 16);
    pq.w = (u32)f2bf(qo[6]) | ((u32)f2bf(qo[7]) << 16);
    pk.x = (u32)f2bf(ko[0]) | ((u32)f2bf(ko[1]) << 16);
    pk.y = (u32)f2bf(ko[2]) | ((u32)f2bf(ko[3]) << 16);
    pk.z = (u32)f2bf(ko[4]) | ((u32)f2bf(ko[5]) << 16);
    pk.w = (u32)f2bf(ko[6]) | ((u32)f2bf(ko[7]) << 16);
    *(uint4*)&qout[obase] = pq;
    *(uint4*)&kout[obase] = pk;
    *(uint4*)&vout[obase] = va;   // v: pass-through (already bf16)
}

// ---------------- V transpose: (BH, N, D) -> (BH, D, N) ----------------
__global__ __launch_bounds__(256) void k_vtrans(const u16* __restrict__ V, u16* __restrict__ Vt){
    __shared__ u16 t[64 * 66];
    const int bh = blockIdx.z;
    const int n0 = blockIdx.x * 64, d0 = blockIdx.y * 64;
    const int tid = threadIdx.x;
    const int q = tid & 7, p = tid >> 3;
    #pragma unroll
    for (int it = 0; it < 2; it++){
        int r = p + it * 32;
        const u16* src = V + ((size_t)bh * NN + n0 + r) * DD + d0 + q * 8;
        uint4 v = *(const uint4*)src;
        u32* dst = (u32*)&t[r * 66 + q * 8];
        dst[0] = v.x; dst[1] = v.y; dst[2] = v.z; dst[3] = v.w;
    }
    __syncthreads();
    #pragma unroll
    for (int it = 0; it < 2; it++){
        int rd = p + it * 32;
        u16 o[8];
        #pragma unroll
        for (int j = 0; j < 8; j++) o[j] = t[(q * 8 + j) * 66 + rd];
        *(uint4*)(Vt + ((size_t)bh * DD + d0 + rd) * NN + n0 + q * 8) = *(uint4*)o;
    }
}

// ---------------- attention v4: 4 waves/block, 32 q-rows/wave, K reg-prefetch ----------------
__global__ __launch_bounds__(256) void k_attn4(
    const u16* __restrict__ Q, const u16* __restrict__ Kt, const u16* __restrict__ Vt2,
    u16* __restrict__ O)
{
    const int w = threadIdx.x >> 6, lane = threadIdx.x & 63;
    const int l15 = lane & 15, g = lane >> 4;
    // bijective XCD swizzle over 512 blocks: 64 consecutive lids per XCD -> 4 heads/XCD in L2
    const int flat = blockIdx.x;
    const int lid  = (flat & 7) * 64 + (flat >> 3);
    const int qt = lid & 15;
    const int h  = (lid >> 4) & 15;
    const int b  = lid >> 8;
    const size_t hb  = (size_t)(b * HH + h) * NN * DD;  // Q, K: (N,D)
    const size_t hbT = (size_t)(b * HH + h) * DD * NN;  // Vt2: (D,N)
    const int qbase = (qt * 4 + w) * 32;
    const float sc = 0.08838834764831845f * 1.4426950408889634f; // D^-0.5 * log2(e)

    // Q fragments (B operand of S^T = K * Q^T): col = qi = l15, k=d = 32c+8g+j
    bf16x8 qf[2][4];
    #pragma unroll
    for (int u = 0; u < 2; u++){
        const u16* qrow = Q + hb + (size_t)(qbase + u * 16 + l15) * DD;
        #pragma unroll
        for (int c = 0; c < 4; c++)
            qf[u][c] = *(const bf16x8*)(qrow + c * 32 + 8 * g);
    }

    f32x4 oacc[2][8];
    #pragma unroll
    for (int u = 0; u < 2; u++)
        #pragma unroll
        for (int tb = 0; tb < 8; tb++){ f32x4 z = {0.f,0.f,0.f,0.f}; oacc[u][tb] = z; }
    float lsum0 = 0.f, lsum1 = 0.f;

    // kj-interleave: tile0 rows kj=8*(m>>2)+(m&3), tile1 +4 -> lane's C-regs = contiguous kj 8g..8g+7
    const int mperm = 8 * (l15 >> 2) + (l15 & 3);

    auto loadK = [&](int kv0, bf16x8 (&kf)[2][4]){
        const u16* k0row = Kt + hb + (size_t)(kv0 + mperm) * DD;
        #pragma unroll
        for (int c = 0; c < 4; c++){
            kf[0][c] = *(const bf16x8*)(k0row + c * 32 + 8 * g);
            kf[1][c] = *(const bf16x8*)(k0row + 4 * DD + c * 32 + 8 * g);
        }
    };
    auto loadV = [&](int kv0, bf16x8 (&vf)[8]){
        #pragma unroll
        for (int tb = 0; tb < 8; tb++)
            vf[tb] = *(const bf16x8*)(Vt2 + hbT + (size_t)(tb * 16 + l15) * NN + kv0 + 8 * g);
    };
    auto step = [&](const bf16x8 (&kf)[2][4], const bf16x8 (&vf)[8]){
        f32x4 st00 = {0,0,0,0}, st01 = {0,0,0,0}, st10 = {0,0,0,0}, st11 = {0,0,0,0};
        #pragma unroll
        for (int c = 0; c < 4; c++){
            st00 = MFMA(kf[0][c], qf[0][c], st00);
            st01 = MFMA(kf[0][c], qf[1][c], st01);
            st10 = MFMA(kf[1][c], qf[0][c], st10);
            st11 = MFMA(kf[1][c], qf[1][c], st11);
        }
        u16x8 pu0, pu1;
        #pragma unroll
        for (int r = 0; r < 4; r++){
            u16 a0 = f2bf(exp2f(st00[r] * sc));
            u16 a1 = f2bf(exp2f(st10[r] * sc));
            pu0[r] = a0; pu0[r + 4] = a1;
            lsum0 += bf2f(a0) + bf2f(a1);
            u16 b0 = f2bf(exp2f(st01[r] * sc));
            u16 b1 = f2bf(exp2f(st11[r] * sc));
            pu1[r] = b0; pu1[r + 4] = b1;
            lsum1 += bf2f(b0) + bf2f(b1);
        }
        bf16x8 pf0 = __builtin_bit_cast(bf16x8, pu0);
        bf16x8 pf1 = __builtin_bit_cast(bf16x8, pu1);
        #pragma unroll
        for (int tb = 0; tb < 8; tb++){
            oacc[0][tb] = MFMA(pf0, vf[tb], oacc[0][tb]);
            oacc[1][tb] = MFMA(pf1, vf[tb], oacc[1][tb]);
        }
    };

    // software pipeline: K double-buffered one half-iter ahead; V issued before QK of its half
    bf16x8 ka[2][4], kb[2][4];
    loadK(0, ka);
    for (int kv0 = 0; kv0 < NN; kv0 += 64){
        bf16x8 va[8];
        loadV(kv0, va);              // V first (oldest) -> counted vmcnt leaves K-next in flight
        loadK(kv0 + 32, kb);
        step(ka, va);
        bf16x8 vb[8];
        loadV(kv0 + 32, vb);
        loadK((kv0 + 64) & (NN - 1), ka);   // wraps to 0 on last iter (harmless)
        step(kb, vb);
    }

    lsum0 += __shfl_xor(lsum0, 16); lsum0 += __shfl_xor(lsum0, 32);
    lsum1 += __shfl_xor(lsum1, 16); lsum1 += __shfl_xor(lsum1, 32);
    float linv0 = 1.f / lsum0, linv1 = 1.f / lsum1;
    float li0[4], li1[4];
    #pragma unroll
    for (int r = 0; r < 4; r++){
        li0[r] = __shfl(linv0, 4 * g + r);
        li1[r] = __shfl(linv1, 4 * g + r);
    }

    #pragma unroll
    for (int tb = 0; tb < 8; tb++){
        #pragma unroll
        for (int r = 0; r < 4; r++){
            int q0 = qbase + 4 * g + r;
            O[(size_t)(b * NN + q0) * CC + h * DD + tb * 16 + l15] = f2bf(oacc[0][tb][r] * li0[r]);
            int q1 = qbase + 16 + 4 * g + r;
            O[(size_t)(b * NN + q1) * CC + h * DD + tb * 16 + l15] = f2bf(oacc[1][tb][r] * li1[r]);
        }
    }
}

// ---------------- launch ----------------
extern "C" void kernel_launch(void* const* d_in, const int* in_sizes, int n_in,
                              void* d_out, int out_size, void* d_ws, size_t ws_size,
                              hipStream_t stream) {
    const float* x      = (const float*)d_in[0];
    const float* w_qkv  = (const float*)d_in[1];
    const float* qw     = (const float*)d_in[2];
    const float* kw     = (const float*)d_in[3];
    const float* cosb   = (const float*)d_in[4];
    const float* sinb   = (const float*)d_in[5];
    const float* w_proj = (const float*)d_in[6];
    const float* b_proj = (const float*)d_in[7];
    float* out = (float*)d_out;

    const size_t sz_xhi  = (size_t)MM * CC * 2;        // 16 MiB
    const size_t sz_wqkv = (size_t)FF * CC * 2;        // 24 MiB
    const size_t sz_wprj = (size_t)CC * CC * 2;        // 8 MiB
    const size_t sz_qkv  = (size_t)MM * FF * 2;        // 48 MiB
    const size_t sz_t    = (size_t)BB * HH * NN * DD * 2; // 16 MiB each
    const size_t need = sz_xhi*2 + sz_wqkv + sz_wprj + sz_qkv + sz_t*3 + sz_xhi;
    if (ws_size < need) return;

    char* ws = (char*)d_ws;
    size_t off = 0;
    auto alloc = [&](size_t bytes){ void* p = ws + off; off += (bytes + 255) & ~(size_t)255; return p; };
    u16* x_hi    = (u16*)alloc(sz_xhi);
    u16* x_lo    = (u16*)alloc(sz_xhi);
    u16* wqkv_bf = (u16*)alloc(sz_wqkv);
    u16* wprj_bf = (u16*)alloc(sz_wprj);
    u16* qkv     = (u16*)alloc(sz_qkv);
    u16* qr      = (u16*)alloc(sz_t);
    u16* kr      = (u16*)alloc(sz_t);
    u16* vt      = (u16*)alloc(sz_t);
    u16* ob      = (u16*)alloc(sz_xhi);
    u16* vt2     = qkv;   // qkv is dead after k_norm_rope; reuse for transposed V

    k_split_x<<<2048, 256, 0, stream>>>(x, x_hi, x_lo, MM * CC / 4);
    k_f2bf<<<2048, 256, 0, stream>>>(w_qkv, wqkv_bf, FF * CC / 4);
    k_f2bf<<<1024, 256, 0, stream>>>(w_proj, wprj_bf, CC * CC / 4);
    k_gemm_bt<1, 1><<<dim3(FF / 128, MM / 128), 256, 0, stream>>>(
        x_hi, x_lo, wqkv_bf, nullptr, qkv, nullptr, MM, FF, CC);
    k_norm_rope<<<MM, 256, 0, stream>>>(qkv, qw, kw, cosb, sinb, qr, kr, vt);
    k_vtrans<<<dim3(NN / 64, DD / 64, BB * HH), 256, 0, stream>>>(vt, vt2);
    k_attn4<<<512, 256, 0, stream>>>(qr, kr, vt2, ob);
    k_gemm_bt<0, 0><<<dim3(CC / 128, MM / 128), 256, 0, stream>>>(
        ob, nullptr, wprj_bf, out, nullptr, b_proj, MM, CC, CC);
}

// Round 5
// 412.520 us; speedup vs baseline: 1.4569x; 1.3084x over previous
//
#include <hip/hip_runtime.h>
#include <stdint.h>

typedef unsigned short u16;
typedef unsigned int   u32;
typedef __bf16 bf16_t;
typedef bf16_t bf16x4 __attribute__((ext_vector_type(4)));
typedef bf16_t bf16x8 __attribute__((ext_vector_type(8)));
typedef float  f32x4  __attribute__((ext_vector_type(4)));
typedef u16    u16x8  __attribute__((ext_vector_type(8)));

#define BB 2
#define NN 2048
#define CC 2048
#define HH 16
#define DD 128
#define FF 6144
#define MM 4096

__device__ __forceinline__ u16 f2bf(float f){
    u32 u = __builtin_bit_cast(u32, f);
    u32 r = (u + 0x7fffu + ((u >> 16) & 1u)) >> 16;
    return (u16)r;
}
__device__ __forceinline__ float bf2f(u16 h){
    u32 u = ((u32)h) << 16;
    return __builtin_bit_cast(float, u);
}
__device__ __forceinline__ f32x4 MFMA(bf16x8 a, bf16x8 b, f32x4 c){
    return __builtin_amdgcn_mfma_f32_16x16x32_bf16(a, b, c, 0, 0, 0);
}
__device__ __forceinline__ void gld16(const void* g, void* l){
    __builtin_amdgcn_global_load_lds(
        (const __attribute__((address_space(1))) void*)(g),
        (__attribute__((address_space(3))) void*)(l), 16, 0, 0);
}

// ---------------- conversion kernels ----------------
__global__ void k_split_x(const float* __restrict__ x, u16* __restrict__ xhi,
                          u16* __restrict__ xlo, int n4){
    int i = blockIdx.x * blockDim.x + threadIdx.x;
    int stride = gridDim.x * blockDim.x;
    for (; i < n4; i += stride){
        float4 v = ((const float4*)x)[i];
        u16 h0 = f2bf(v.x), h1 = f2bf(v.y), h2 = f2bf(v.z), h3 = f2bf(v.w);
        ushort4 hi; hi.x = h0; hi.y = h1; hi.z = h2; hi.w = h3;
        ushort4 lo;
        lo.x = f2bf(v.x - bf2f(h0));
        lo.y = f2bf(v.y - bf2f(h1));
        lo.z = f2bf(v.z - bf2f(h2));
        lo.w = f2bf(v.w - bf2f(h3));
        ((ushort4*)xhi)[i] = hi;
        ((ushort4*)xlo)[i] = lo;
    }
}

__global__ void k_f2bf(const float* __restrict__ a, u16* __restrict__ o, int n4){
    int i = blockIdx.x * blockDim.x + threadIdx.x;
    int stride = gridDim.x * blockDim.x;
    for (; i < n4; i += stride){
        float4 v = ((const float4*)a)[i];
        ushort4 r; r.x = f2bf(v.x); r.y = f2bf(v.y); r.z = f2bf(v.z); r.w = f2bf(v.w);
        ((ushort4*)o)[i] = r;
    }
}

// ---------------- GEMM:  out[m][n] = sum_k A[m][k] * Bw[n][k]  ----------------
template<int SPLIT, int OUTBF>
__global__ __launch_bounds__(256) void k_gemm_bt(
    const u16* __restrict__ A, const u16* __restrict__ A2,
    const u16* __restrict__ Bw, float* __restrict__ outf, u16* __restrict__ outb,
    const float* __restrict__ bias, int M, int N, int K)
{
    __shared__ u16 As [128 * 32];
    __shared__ u16 Bs [128 * 32];
    __shared__ u16 A2s[SPLIT ? 128 * 32 : 64];
    const int tid  = threadIdx.x;
    const int brow = blockIdx.y * 128;
    const int bcol = blockIdx.x * 128;
    const int w = tid >> 6, lane = tid & 63;
    const int wr = w >> 1, wc = w & 1;
    const int l15 = lane & 15, g = lane >> 4;
    const int sr = tid >> 2;            // 0..63
    const int sc_ = (tid & 3) * 8;      // 0,8,16,24

    f32x4 acc[4][4];
    #pragma unroll
    for (int i = 0; i < 4; i++)
        #pragma unroll
        for (int j = 0; j < 4; j++){
            f32x4 z = {0.f, 0.f, 0.f, 0.f};
            acc[i][j] = z;
        }

    for (int k0 = 0; k0 < K; k0 += 32){
        __syncthreads();
        gld16(&Bw[(size_t)(bcol + sr) * K + k0 + sc_],      &Bs[w * 512]);
        gld16(&Bw[(size_t)(bcol + sr + 64) * K + k0 + sc_], &Bs[2048 + w * 512]);
        gld16(&A [(size_t)(brow + sr) * K + k0 + sc_],      &As[w * 512]);
        gld16(&A [(size_t)(brow + sr + 64) * K + k0 + sc_], &As[2048 + w * 512]);
        if (SPLIT){
            gld16(&A2[(size_t)(brow + sr) * K + k0 + sc_],      &A2s[w * 512]);
            gld16(&A2[(size_t)(brow + sr + 64) * K + k0 + sc_], &A2s[2048 + w * 512]);
        }
        __syncthreads();
        bf16x8 fb[4];
        #pragma unroll
        for (int j = 0; j < 4; j++){
            int row = wc * 64 + j * 16 + l15;
            fb[j] = *(const bf16x8*)&Bs[row * 32 + 8 * g];
        }
        #pragma unroll
        for (int i = 0; i < 4; i++){
            int row = wr * 64 + i * 16 + l15;
            bf16x8 fa = *(const bf16x8*)&As[row * 32 + 8 * g];
            #pragma unroll
            for (int j = 0; j < 4; j++) acc[i][j] = MFMA(fa, fb[j], acc[i][j]);
            if (SPLIT){
                bf16x8 fa2 = *(const bf16x8*)&A2s[row * 32 + 8 * g];
                #pragma unroll
                for (int j = 0; j < 4; j++) acc[i][j] = MFMA(fa2, fb[j], acc[i][j]);
            }
        }
    }

    #pragma unroll
    for (int i = 0; i < 4; i++){
        #pragma unroll
        for (int j = 0; j < 4; j++){
            int colg = bcol + wc * 64 + j * 16 + l15;
            #pragma unroll
            for (int r = 0; r < 4; r++){
                int rowg = brow + wr * 64 + i * 16 + 4 * g + r;
                float v = acc[i][j][r];
                if (OUTBF) outb[(size_t)rowg * N + colg] = f2bf(v);
                else       outf[(size_t)rowg * N + colg] = v + bias[colg];
            }
        }
    }
}

// ---------------- RMSNorm + RoPE + transpose to (B,H,N,D) ----------------
// NOTE: q is pre-scaled by D^-0.5 * log2(e) so attention can exp2 directly.
__global__ __launch_bounds__(256) void k_norm_rope(
    const u16* __restrict__ qkv, const float* __restrict__ qw, const float* __restrict__ kw,
    const float* __restrict__ cosb, const float* __restrict__ sinb,
    u16* __restrict__ qout, u16* __restrict__ kout, u16* __restrict__ vout)
{
    const int m = blockIdx.x;           // 0..4095  (b*N + n)
    const int b = m >> 11;
    const int n = m & 2047;
    const int t = threadIdx.x;
    const size_t base = (size_t)m * FF;
    const int e0 = t * 8;
    const float SCL = 0.08838834764831845f * 1.4426950408889634f;

    float qv[8], kvv[8];
    uint4 qa = *(const uint4*)&qkv[base + e0];
    uint4 ka = *(const uint4*)&qkv[base + CC + e0];
    uint4 va = *(const uint4*)&qkv[base + 2 * CC + e0];
    {
        u32 aa[4] = {qa.x, qa.y, qa.z, qa.w};
        u32 bb[4] = {ka.x, ka.y, ka.z, ka.w};
        #pragma unroll
        for (int i = 0; i < 4; i++){
            qv[2*i]   = bf2f((u16)(aa[i] & 0xffff));
            qv[2*i+1] = bf2f((u16)(aa[i] >> 16));
            kvv[2*i]   = bf2f((u16)(bb[i] & 0xffff));
            kvv[2*i+1] = bf2f((u16)(bb[i] >> 16));
        }
    }
    float sq = 0.f, sk = 0.f;
    #pragma unroll
    for (int i = 0; i < 8; i++){ sq += qv[i]*qv[i]; sk += kvv[i]*kvv[i]; }
    #pragma unroll
    for (int o = 32; o > 0; o >>= 1){ sq += __shfl_xor(sq, o); sk += __shfl_xor(sk, o); }
    __shared__ float red[8];
    if ((t & 63) == 0){ red[(t >> 6)*2] = sq; red[(t >> 6)*2 + 1] = sk; }
    __syncthreads();
    sq = red[0] + red[2] + red[4] + red[6];
    sk = red[1] + red[3] + red[5] + red[7];
    const float rq = rsqrtf(sq * (1.f / 2048.f) + 1e-5f);
    const float rk = rsqrtf(sk * (1.f / 2048.f) + 1e-5f);

    const int h  = t >> 4;
    const int d0 = (t & 15) * 8;
    const float* cp = cosb + (size_t)n * DD + d0;
    const float* sp = sinb + (size_t)n * DD + d0;
    float qo[8], ko[8];
    #pragma unroll
    for (int j = 0; j < 8; j += 2){
        float c0 = cp[j], c1 = cp[j+1], s0 = sp[j], s1 = sp[j+1];
        float x0 = qv[j]   * rq * qw[e0 + j];
        float x1 = qv[j+1] * rq * qw[e0 + j + 1];
        qo[j]   = (x0 * c0 - x1 * s0) * SCL;
        qo[j+1] = (x1 * c1 + x0 * s1) * SCL;
        float y0 = kvv[j]   * rk * kw[e0 + j];
        float y1 = kvv[j+1] * rk * kw[e0 + j + 1];
        ko[j]   = y0 * c0 - y1 * s0;
        ko[j+1] = y1 * c1 + y0 * s1;
    }
    const size_t obase = ((size_t)(b * HH + h) * NN + n) * DD + d0;
    uint4 pq, pk;
    pq.x = (u32)f2bf(qo[0]) | ((u32)f2bf(qo[1]) << 16);
    pq.y = (u32)f2bf(qo[2]) | ((u32)f2bf(qo[3]) << 16);
    pq.z = (u32)f2bf(qo[4]) | ((u32)f2bf(qo[5]) << 16);
    pq.w = (u32)f2bf(qo[6]) | ((u32)f2bf(qo[7]) << 16);
    pk.x = (u32)f2bf(ko[0]) | ((u32)f2bf(ko[1]) << 16);
    pk.y = (u32)f2bf(ko[2]) | ((u32)f2bf(ko[3]) << 16);
    pk.z = (u32)f2bf(ko[4]) | ((u32)f2bf(ko[5]) << 16);
    pk.w = (u32)f2bf(ko[6]) | ((u32)f2bf(ko[7]) << 16);
    *(uint4*)&qout[obase] = pq;
    *(uint4*)&kout[obase] = pk;
    *(uint4*)&vout[obase] = va;   // v: pass-through (already bf16)
}

// ---------------- V transpose: (BH, N, D) -> (BH, D, N) ----------------
__global__ __launch_bounds__(256) void k_vtrans(const u16* __restrict__ V, u16* __restrict__ Vt){
    __shared__ u16 t[64 * 66];
    const int bh = blockIdx.z;
    const int n0 = blockIdx.x * 64, d0 = blockIdx.y * 64;
    const int tid = threadIdx.x;
    const int q = tid & 7, p = tid >> 3;
    #pragma unroll
    for (int it = 0; it < 2; it++){
        int r = p + it * 32;
        const u16* src = V + ((size_t)bh * NN + n0 + r) * DD + d0 + q * 8;
        uint4 v = *(const uint4*)src;
        u32* dst = (u32*)&t[r * 66 + q * 8];
        dst[0] = v.x; dst[1] = v.y; dst[2] = v.z; dst[3] = v.w;
    }
    __syncthreads();
    #pragma unroll
    for (int it = 0; it < 2; it++){
        int rd = p + it * 32;
        u16 o[8];
        #pragma unroll
        for (int j = 0; j < 8; j++) o[j] = t[(q * 8 + j) * 66 + rd];
        *(uint4*)(Vt + ((size_t)bh * DD + d0 + rd) * NN + n0 + q * 8) = *(uint4*)o;
    }
}

// ---------------- attention v5: LDS-staged K/V (fragment-order), 2-phase dbuf ----------------
// Block: 4 waves x 32 q-rows = 128 q-rows of one (b,h). kv-tile 64.
// LDS layout: fragment-sequential slots of 1024B; slot content = exactly the
// bf16x8 each lane reads at base+lane*16 (mperm baked into the GLOBAL source).
__global__ __launch_bounds__(256, 2) void k_attn5(
    const u16* __restrict__ Q, const u16* __restrict__ Kt, const u16* __restrict__ Vt2,
    u16* __restrict__ O)
{
    __shared__ u16 Kbuf[2][8192];   // 16 slots: s = hh*8 + t*4 + c
    __shared__ u16 Vbuf[2][8192];   // 16 slots: s = hh*8 + tb
    const int tid = threadIdx.x;
    const int w = tid >> 6, lane = tid & 63;
    const int l15 = lane & 15, g = lane >> 4;
    const int flat = blockIdx.x;
    const int lid  = (flat & 7) * 64 + (flat >> 3);   // bijective XCD swizzle (512 blocks)
    const int qb = lid & 15;
    const int h  = (lid >> 4) & 15;
    const int b  = lid >> 8;
    const size_t hb  = (size_t)(b * HH + h) * NN * DD;  // Q, K: (N,D)
    const size_t hbT = (size_t)(b * HH + h) * DD * NN;  // Vt2: (D,N)
    const int qbase = qb * 128 + w * 32;
    const int mperm = 8 * (l15 >> 2) + (l15 & 3);

    // Q fragments (pre-scaled by sc*log2e in k_norm_rope)
    bf16x8 qf[2][4];
    #pragma unroll
    for (int u = 0; u < 2; u++){
        const u16* qrow = Q + hb + (size_t)(qbase + u * 16 + l15) * DD;
        #pragma unroll
        for (int c = 0; c < 4; c++)
            qf[u][c] = *(const bf16x8*)(qrow + c * 32 + 8 * g);
    }

    f32x4 oacc[2][8];
    #pragma unroll
    for (int u = 0; u < 2; u++)
        #pragma unroll
        for (int tb = 0; tb < 8; tb++){ f32x4 z = {0.f,0.f,0.f,0.f}; oacc[u][tb] = z; }
    float lsum0 = 0.f, lsum1 = 0.f;

    // stage K-tile (16 KB) + V-tile (16 KB) for kv0..kv0+63 into buf
    auto stage = [&](int buf, int kv0){
        #pragma unroll
        for (int it = 0; it < 8; it++){
            int s = it * 4 + w;                 // 0..31, each slot once
            if (s < 16){
                int hh = s >> 3, t = (s >> 2) & 1, c = s & 3;
                gld16(&Kt[hb + (size_t)(kv0 + 32 * hh + 4 * t + mperm) * DD + 32 * c + 8 * g],
                      &Kbuf[buf][s * 512]);
            } else {
                int s2 = s - 16;
                int hh = s2 >> 3, tb = s2 & 7;
                gld16(&Vt2[hbT + (size_t)(tb * 16 + l15) * NN + kv0 + 32 * hh + 8 * g],
                      &Vbuf[buf][s2 * 512]);
            }
        }
    };

    int cur = 0;
    stage(0, 0);
    for (int kv0 = 0; kv0 < NN; kv0 += 64){
        __syncthreads();                         // buf[cur] staged; prev reads done
        if (kv0 + 64 < NN) stage(cur ^ 1, kv0 + 64);
        const u16* kb = &Kbuf[cur][0] + lane * 8;
        const u16* vb = &Vbuf[cur][0] + lane * 8;
        #pragma unroll
        for (int hh = 0; hh < 2; hh++){
            f32x4 st00 = {0,0,0,0}, st01 = {0,0,0,0}, st10 = {0,0,0,0}, st11 = {0,0,0,0};
            #pragma unroll
            for (int c = 0; c < 4; c++){
                bf16x8 kf0 = *(const bf16x8*)(kb + (hh * 8 + c) * 512);
                bf16x8 kf1 = *(const bf16x8*)(kb + (hh * 8 + 4 + c) * 512);
                st00 = MFMA(kf0, qf[0][c], st00);
                st01 = MFMA(kf0, qf[1][c], st01);
                st10 = MFMA(kf1, qf[0][c], st10);
                st11 = MFMA(kf1, qf[1][c], st11);
            }
            bf16x8 pf0, pf1;
            #pragma unroll
            for (int r = 0; r < 4; r++){
                float e00 = exp2f(st00[r]), e10 = exp2f(st10[r]);
                float e01 = exp2f(st01[r]), e11 = exp2f(st11[r]);
                lsum0 += e00 + e10;
                lsum1 += e01 + e11;
                pf0[r] = (bf16_t)e00; pf0[r + 4] = (bf16_t)e10;
                pf1[r] = (bf16_t)e01; pf1[r + 4] = (bf16_t)e11;
            }
            #pragma unroll
            for (int tb = 0; tb < 8; tb++){
                bf16x8 vf = *(const bf16x8*)(vb + (hh * 8 + tb) * 512);
                oacc[0][tb] = MFMA(pf0, vf, oacc[0][tb]);
                oacc[1][tb] = MFMA(pf1, vf, oacc[1][tb]);
            }
        }
        cur ^= 1;
    }

    lsum0 += __shfl_xor(lsum0, 16); lsum0 += __shfl_xor(lsum0, 32);
    lsum1 += __shfl_xor(lsum1, 16); lsum1 += __shfl_xor(lsum1, 32);
    float linv0 = 1.f / lsum0, linv1 = 1.f / lsum1;
    float li0[4], li1[4];
    #pragma unroll
    for (int r = 0; r < 4; r++){
        li0[r] = __shfl(linv0, 4 * g + r);
        li1[r] = __shfl(linv1, 4 * g + r);
    }

    #pragma unroll
    for (int tb = 0; tb < 8; tb++){
        #pragma unroll
        for (int r = 0; r < 4; r++){
            int q0 = qbase + 4 * g + r;
            O[(size_t)(b * NN + q0) * CC + h * DD + tb * 16 + l15] = f2bf(oacc[0][tb][r] * li0[r]);
            int q1 = qbase + 16 + 4 * g + r;
            O[(size_t)(b * NN + q1) * CC + h * DD + tb * 16 + l15] = f2bf(oacc[1][tb][r] * li1[r]);
        }
    }
}

// ---------------- launch ----------------
extern "C" void kernel_launch(void* const* d_in, const int* in_sizes, int n_in,
                              void* d_out, int out_size, void* d_ws, size_t ws_size,
                              hipStream_t stream) {
    const float* x      = (const float*)d_in[0];
    const float* w_qkv  = (const float*)d_in[1];
    const float* qw     = (const float*)d_in[2];
    const float* kw     = (const float*)d_in[3];
    const float* cosb   = (const float*)d_in[4];
    const float* sinb   = (const float*)d_in[5];
    const float* w_proj = (const float*)d_in[6];
    const float* b_proj = (const float*)d_in[7];
    float* out = (float*)d_out;

    const size_t sz_xhi  = (size_t)MM * CC * 2;        // 16 MiB
    const size_t sz_wqkv = (size_t)FF * CC * 2;        // 24 MiB
    const size_t sz_wprj = (size_t)CC * CC * 2;        // 8 MiB
    const size_t sz_qkv  = (size_t)MM * FF * 2;        // 48 MiB
    const size_t sz_t    = (size_t)BB * HH * NN * DD * 2; // 16 MiB each
    const size_t need = sz_xhi*2 + sz_wqkv + sz_wprj + sz_qkv + sz_t*3 + sz_xhi;
    if (ws_size < need) return;

    char* ws = (char*)d_ws;
    size_t off = 0;
    auto alloc = [&](size_t bytes){ void* p = ws + off; off += (bytes + 255) & ~(size_t)255; return p; };
    u16* x_hi    = (u16*)alloc(sz_xhi);
    u16* x_lo    = (u16*)alloc(sz_xhi);
    u16* wqkv_bf = (u16*)alloc(sz_wqkv);
    u16* wprj_bf = (u16*)alloc(sz_wprj);
    u16* qkv     = (u16*)alloc(sz_qkv);
    u16* qr      = (u16*)alloc(sz_t);
    u16* kr      = (u16*)alloc(sz_t);
    u16* vt      = (u16*)alloc(sz_t);
    u16* ob      = (u16*)alloc(sz_xhi);
    u16* vt2     = qkv;   // qkv is dead after k_norm_rope; reuse for transposed V

    k_split_x<<<2048, 256, 0, stream>>>(x, x_hi, x_lo, MM * CC / 4);
    k_f2bf<<<2048, 256, 0, stream>>>(w_qkv, wqkv_bf, FF * CC / 4);
    k_f2bf<<<1024, 256, 0, stream>>>(w_proj, wprj_bf, CC * CC / 4);
    k_gemm_bt<1, 1><<<dim3(FF / 128, MM / 128), 256, 0, stream>>>(
        x_hi, x_lo, wqkv_bf, nullptr, qkv, nullptr, MM, FF, CC);
    k_norm_rope<<<MM, 256, 0, stream>>>(qkv, qw, kw, cosb, sinb, qr, kr, vt);
    k_vtrans<<<dim3(NN / 64, DD / 64, BB * HH), 256, 0, stream>>>(vt, vt2);
    k_attn5<<<512, 256, 0, stream>>>(qr, kr, vt2, ob);
    k_gemm_bt<0, 0><<<dim3(CC / 128, MM / 128), 256, 0, stream>>>(
        ob, nullptr, wprj_bf, out, nullptr, b_proj, MM, CC, CC);
}

// Round 6
// 343.980 us; speedup vs baseline: 1.7472x; 1.1993x over previous
//
#include <hip/hip_runtime.h>
#include <stdint.h>

typedef unsigned short u16;
typedef unsigned int   u32;
typedef _Float16 f16_t;
typedef f16_t f16x8 __attribute__((ext_vector_type(8)));
typedef float  f32x4  __attribute__((ext_vector_type(4)));

#define BB 2
#define NN 2048
#define CC 2048
#define HH 16
#define DD 128
#define FF 6144
#define MM 4096

__device__ __forceinline__ u16 f2h(float f){
    f16_t h = (f16_t)f;
    return __builtin_bit_cast(u16, h);
}
__device__ __forceinline__ float h2f(u16 b){
    return (float)__builtin_bit_cast(f16_t, b);
}
__device__ __forceinline__ f32x4 MFMA(f16x8 a, f16x8 b, f32x4 c){
    return __builtin_amdgcn_mfma_f32_16x16x32_f16(a, b, c, 0, 0, 0);
}
__device__ __forceinline__ void gld16(const void* g, void* l){
    __builtin_amdgcn_global_load_lds(
        (const __attribute__((address_space(1))) void*)(g),
        (__attribute__((address_space(3))) void*)(l), 16, 0, 0);
}

// ---------------- fp32 -> fp16 conversion ----------------
__global__ void k_f2h(const float* __restrict__ a, u16* __restrict__ o, int n4){
    int i = blockIdx.x * blockDim.x + threadIdx.x;
    int stride = gridDim.x * blockDim.x;
    for (; i < n4; i += stride){
        float4 v = ((const float4*)a)[i];
        ushort4 r; r.x = f2h(v.x); r.y = f2h(v.y); r.z = f2h(v.z); r.w = f2h(v.w);
        ((ushort4*)o)[i] = r;
    }
}

// ---------------- GEMM:  out[m][n] = sum_k A[m][k] * Bw[n][k]  (fp16 MFMA) ------
// LDS XOR swizzle: phys col-block g_p = g ^ ((row>>1)&3); applied to the GLOBAL
// source during global_load_lds (dest linear) and to the ds_read address.
template<int OUTH>
__global__ __launch_bounds__(256) void k_gemm_bt(
    const u16* __restrict__ A, const u16* __restrict__ Bw,
    float* __restrict__ outf, u16* __restrict__ outb,
    const float* __restrict__ bias, int M, int N, int K)
{
    __shared__ u16 As[128 * 32];
    __shared__ u16 Bs[128 * 32];
    const int tid  = threadIdx.x;
    const int brow = blockIdx.y * 128;
    const int bcol = blockIdx.x * 128;
    const int w = tid >> 6, lane = tid & 63;
    const int wr = w >> 1, wc = w & 1;
    const int l15 = lane & 15, g = lane >> 4;
    const int sr  = tid >> 2;                               // staged row 0..63 (+64)
    const int scz = ((tid & 3) ^ ((tid >> 3) & 3)) * 8;     // swizzled source col-block
    const int gx  = (g ^ ((l15 >> 1) & 3)) * 8;             // swizzled read col offset

    f32x4 acc[4][4];
    #pragma unroll
    for (int i = 0; i < 4; i++)
        #pragma unroll
        for (int j = 0; j < 4; j++){
            f32x4 z = {0.f, 0.f, 0.f, 0.f};
            acc[i][j] = z;
        }

    for (int k0 = 0; k0 < K; k0 += 32){
        __syncthreads();
        gld16(&Bw[(size_t)(bcol + sr) * K + k0 + scz],      &Bs[w * 512]);
        gld16(&Bw[(size_t)(bcol + sr + 64) * K + k0 + scz], &Bs[2048 + w * 512]);
        gld16(&A [(size_t)(brow + sr) * K + k0 + scz],      &As[w * 512]);
        gld16(&A [(size_t)(brow + sr + 64) * K + k0 + scz], &As[2048 + w * 512]);
        __syncthreads();
        f16x8 fb[4];
        #pragma unroll
        for (int j = 0; j < 4; j++){
            int row = wc * 64 + j * 16 + l15;
            fb[j] = *(const f16x8*)&Bs[row * 32 + gx];
        }
        #pragma unroll
        for (int i = 0; i < 4; i++){
            int row = wr * 64 + i * 16 + l15;
            f16x8 fa = *(const f16x8*)&As[row * 32 + gx];
            #pragma unroll
            for (int j = 0; j < 4; j++) acc[i][j] = MFMA(fa, fb[j], acc[i][j]);
        }
    }

    #pragma unroll
    for (int i = 0; i < 4; i++){
        #pragma unroll
        for (int j = 0; j < 4; j++){
            int colg = bcol + wc * 64 + j * 16 + l15;
            #pragma unroll
            for (int r = 0; r < 4; r++){
                int rowg = brow + wr * 64 + i * 16 + 4 * g + r;
                float v = acc[i][j][r];
                if (OUTH) outb[(size_t)rowg * N + colg] = f2h(v);
                else      outf[(size_t)rowg * N + colg] = v + bias[colg];
            }
        }
    }
}

// ---------------- RMSNorm + RoPE + transpose to (B,H,N,D), fp16 ----------------
// q is pre-scaled by D^-0.5 * log2(e) so attention can exp2 directly.
__global__ __launch_bounds__(256) void k_norm_rope(
    const u16* __restrict__ qkv, const float* __restrict__ qw, const float* __restrict__ kw,
    const float* __restrict__ cosb, const float* __restrict__ sinb,
    u16* __restrict__ qout, u16* __restrict__ kout, u16* __restrict__ vout)
{
    const int m = blockIdx.x;           // 0..4095  (b*N + n)
    const int b = m >> 11;
    const int n = m & 2047;
    const int t = threadIdx.x;
    const size_t base = (size_t)m * FF;
    const int e0 = t * 8;
    const float SCL = 0.08838834764831845f * 1.4426950408889634f;

    float qv[8], kvv[8];
    uint4 qa = *(const uint4*)&qkv[base + e0];
    uint4 ka = *(const uint4*)&qkv[base + CC + e0];
    uint4 va = *(const uint4*)&qkv[base + 2 * CC + e0];
    {
        u32 aa[4] = {qa.x, qa.y, qa.z, qa.w};
        u32 bb[4] = {ka.x, ka.y, ka.z, ka.w};
        #pragma unroll
        for (int i = 0; i < 4; i++){
            qv[2*i]   = h2f((u16)(aa[i] & 0xffff));
            qv[2*i+1] = h2f((u16)(aa[i] >> 16));
            kvv[2*i]   = h2f((u16)(bb[i] & 0xffff));
            kvv[2*i+1] = h2f((u16)(bb[i] >> 16));
        }
    }
    float sq = 0.f, sk = 0.f;
    #pragma unroll
    for (int i = 0; i < 8; i++){ sq += qv[i]*qv[i]; sk += kvv[i]*kvv[i]; }
    #pragma unroll
    for (int o = 32; o > 0; o >>= 1){ sq += __shfl_xor(sq, o); sk += __shfl_xor(sk, o); }
    __shared__ float red[8];
    if ((t & 63) == 0){ red[(t >> 6)*2] = sq; red[(t >> 6)*2 + 1] = sk; }
    __syncthreads();
    sq = red[0] + red[2] + red[4] + red[6];
    sk = red[1] + red[3] + red[5] + red[7];
    const float rq = rsqrtf(sq * (1.f / 2048.f) + 1e-5f);
    const float rk = rsqrtf(sk * (1.f / 2048.f) + 1e-5f);

    const int h  = t >> 4;
    const int d0 = (t & 15) * 8;
    const float* cp = cosb + (size_t)n * DD + d0;
    const float* sp = sinb + (size_t)n * DD + d0;
    float qo[8], ko[8];
    #pragma unroll
    for (int j = 0; j < 8; j += 2){
        float c0 = cp[j], c1 = cp[j+1], s0 = sp[j], s1 = sp[j+1];
        float x0 = qv[j]   * rq * qw[e0 + j];
        float x1 = qv[j+1] * rq * qw[e0 + j + 1];
        qo[j]   = (x0 * c0 - x1 * s0) * SCL;
        qo[j+1] = (x1 * c1 + x0 * s1) * SCL;
        float y0 = kvv[j]   * rk * kw[e0 + j];
        float y1 = kvv[j+1] * rk * kw[e0 + j + 1];
        ko[j]   = y0 * c0 - y1 * s0;
        ko[j+1] = y1 * c1 + y0 * s1;
    }
    const size_t obase = ((size_t)(b * HH + h) * NN + n) * DD + d0;
    uint4 pq, pk;
    pq.x = (u32)f2h(qo[0]) | ((u32)f2h(qo[1]) << 16);
    pq.y = (u32)f2h(qo[2]) | ((u32)f2h(qo[3]) << 16);
    pq.z = (u32)f2h(qo[4]) | ((u32)f2h(qo[5]) << 16);
    pq.w = (u32)f2h(qo[6]) | ((u32)f2h(qo[7]) << 16);
    pk.x = (u32)f2h(ko[0]) | ((u32)f2h(ko[1]) << 16);
    pk.y = (u32)f2h(ko[2]) | ((u32)f2h(ko[3]) << 16);
    pk.z = (u32)f2h(ko[4]) | ((u32)f2h(ko[5]) << 16);
    pk.w = (u32)f2h(ko[6]) | ((u32)f2h(ko[7]) << 16);
    *(uint4*)&qout[obase] = pq;
    *(uint4*)&kout[obase] = pk;
    *(uint4*)&vout[obase] = va;   // v: pass-through (already fp16)
}

// ---------------- V transpose: (BH, N, D) -> (BH, D, N) ----------------
__global__ __launch_bounds__(256) void k_vtrans(const u16* __restrict__ V, u16* __restrict__ Vt){
    __shared__ u16 t[64 * 66];
    const int bh = blockIdx.z;
    const int n0 = blockIdx.x * 64, d0 = blockIdx.y * 64;
    const int tid = threadIdx.x;
    const int q = tid & 7, p = tid >> 3;
    #pragma unroll
    for (int it = 0; it < 2; it++){
        int r = p + it * 32;
        const u16* src = V + ((size_t)bh * NN + n0 + r) * DD + d0 + q * 8;
        uint4 v = *(const uint4*)src;
        u32* dst = (u32*)&t[r * 66 + q * 8];
        dst[0] = v.x; dst[1] = v.y; dst[2] = v.z; dst[3] = v.w;
    }
    __syncthreads();
    #pragma unroll
    for (int it = 0; it < 2; it++){
        int rd = p + it * 32;
        u16 o[8];
        #pragma unroll
        for (int j = 0; j < 8; j++) o[j] = t[(q * 8 + j) * 66 + rd];
        *(uint4*)(Vt + ((size_t)bh * DD + d0 + rd) * NN + n0 + q * 8) = *(uint4*)o;
    }
}

// ---------------- attention v5: LDS-staged K/V (fragment-order), 2-phase dbuf ----
__global__ __launch_bounds__(256, 2) void k_attn5(
    const u16* __restrict__ Q, const u16* __restrict__ Kt, const u16* __restrict__ Vt2,
    u16* __restrict__ O)
{
    __shared__ u16 Kbuf[2][8192];   // 16 slots: s = hh*8 + t*4 + c
    __shared__ u16 Vbuf[2][8192];   // 16 slots: s = hh*8 + tb
    const int tid = threadIdx.x;
    const int w = tid >> 6, lane = tid & 63;
    const int l15 = lane & 15, g = lane >> 4;
    const int flat = blockIdx.x;
    const int lid  = (flat & 7) * 64 + (flat >> 3);   // bijective XCD swizzle (512 blocks)
    const int qb = lid & 15;
    const int h  = (lid >> 4) & 15;
    const int b  = lid >> 8;
    const size_t hb  = (size_t)(b * HH + h) * NN * DD;  // Q, K: (N,D)
    const size_t hbT = (size_t)(b * HH + h) * DD * NN;  // Vt2: (D,N)
    const int qbase = qb * 128 + w * 32;
    const int mperm = 8 * (l15 >> 2) + (l15 & 3);

    f16x8 qf[2][4];
    #pragma unroll
    for (int u = 0; u < 2; u++){
        const u16* qrow = Q + hb + (size_t)(qbase + u * 16 + l15) * DD;
        #pragma unroll
        for (int c = 0; c < 4; c++)
            qf[u][c] = *(const f16x8*)(qrow + c * 32 + 8 * g);
    }

    f32x4 oacc[2][8];
    #pragma unroll
    for (int u = 0; u < 2; u++)
        #pragma unroll
        for (int tb = 0; tb < 8; tb++){ f32x4 z = {0.f,0.f,0.f,0.f}; oacc[u][tb] = z; }
    float lsum0 = 0.f, lsum1 = 0.f;

    auto stage = [&](int buf, int kv0){
        #pragma unroll
        for (int it = 0; it < 8; it++){
            int s = it * 4 + w;                 // 0..31, each slot once
            if (s < 16){
                int hh = s >> 3, t = (s >> 2) & 1, c = s & 3;
                gld16(&Kt[hb + (size_t)(kv0 + 32 * hh + 4 * t + mperm) * DD + 32 * c + 8 * g],
                      &Kbuf[buf][s * 512]);
            } else {
                int s2 = s - 16;
                int hh = s2 >> 3, tb = s2 & 7;
                gld16(&Vt2[hbT + (size_t)(tb * 16 + l15) * NN + kv0 + 32 * hh + 8 * g],
                      &Vbuf[buf][s2 * 512]);
            }
        }
    };

    int cur = 0;
    stage(0, 0);
    for (int kv0 = 0; kv0 < NN; kv0 += 64){
        __syncthreads();                         // buf[cur] staged; prev reads done
        if (kv0 + 64 < NN) stage(cur ^ 1, kv0 + 64);
        const u16* kb = &Kbuf[cur][0] + lane * 8;
        const u16* vb = &Vbuf[cur][0] + lane * 8;
        #pragma unroll
        for (int hh = 0; hh < 2; hh++){
            f32x4 st00 = {0,0,0,0}, st01 = {0,0,0,0}, st10 = {0,0,0,0}, st11 = {0,0,0,0};
            #pragma unroll
            for (int c = 0; c < 4; c++){
                f16x8 kf0 = *(const f16x8*)(kb + (hh * 8 + c) * 512);
                f16x8 kf1 = *(const f16x8*)(kb + (hh * 8 + 4 + c) * 512);
                st00 = MFMA(kf0, qf[0][c], st00);
                st01 = MFMA(kf0, qf[1][c], st01);
                st10 = MFMA(kf1, qf[0][c], st10);
                st11 = MFMA(kf1, qf[1][c], st11);
            }
            f16x8 pf0, pf1;
            #pragma unroll
            for (int r = 0; r < 4; r++){
                float e00 = exp2f(st00[r]), e10 = exp2f(st10[r]);
                float e01 = exp2f(st01[r]), e11 = exp2f(st11[r]);
                lsum0 += e00 + e10;
                lsum1 += e01 + e11;
                pf0[r] = (f16_t)e00; pf0[r + 4] = (f16_t)e10;
                pf1[r] = (f16_t)e01; pf1[r + 4] = (f16_t)e11;
            }
            #pragma unroll
            for (int tb = 0; tb < 8; tb++){
                f16x8 vf = *(const f16x8*)(vb + (hh * 8 + tb) * 512);
                oacc[0][tb] = MFMA(pf0, vf, oacc[0][tb]);
                oacc[1][tb] = MFMA(pf1, vf, oacc[1][tb]);
            }
        }
        cur ^= 1;
    }

    lsum0 += __shfl_xor(lsum0, 16); lsum0 += __shfl_xor(lsum0, 32);
    lsum1 += __shfl_xor(lsum1, 16); lsum1 += __shfl_xor(lsum1, 32);
    float linv0 = 1.f / lsum0, linv1 = 1.f / lsum1;
    float li0[4], li1[4];
    #pragma unroll
    for (int r = 0; r < 4; r++){
        li0[r] = __shfl(linv0, 4 * g + r);
        li1[r] = __shfl(linv1, 4 * g + r);
    }

    #pragma unroll
    for (int tb = 0; tb < 8; tb++){
        #pragma unroll
        for (int r = 0; r < 4; r++){
            int q0 = qbase + 4 * g + r;
            O[(size_t)(b * NN + q0) * CC + h * DD + tb * 16 + l15] = f2h(oacc[0][tb][r] * li0[r]);
            int q1 = qbase + 16 + 4 * g + r;
            O[(size_t)(b * NN + q1) * CC + h * DD + tb * 16 + l15] = f2h(oacc[1][tb][r] * li1[r]);
        }
    }
}

// ---------------- launch ----------------
extern "C" void kernel_launch(void* const* d_in, const int* in_sizes, int n_in,
                              void* d_out, int out_size, void* d_ws, size_t ws_size,
                              hipStream_t stream) {
    const float* x      = (const float*)d_in[0];
    const float* w_qkv  = (const float*)d_in[1];
    const float* qw     = (const float*)d_in[2];
    const float* kw     = (const float*)d_in[3];
    const float* cosb   = (const float*)d_in[4];
    const float* sinb   = (const float*)d_in[5];
    const float* w_proj = (const float*)d_in[6];
    const float* b_proj = (const float*)d_in[7];
    float* out = (float*)d_out;

    const size_t sz_xh   = (size_t)MM * CC * 2;        // 16 MiB
    const size_t sz_wqkv = (size_t)FF * CC * 2;        // 24 MiB
    const size_t sz_wprj = (size_t)CC * CC * 2;        // 8 MiB
    const size_t sz_qkv  = (size_t)MM * FF * 2;        // 48 MiB
    const size_t sz_t    = (size_t)BB * HH * NN * DD * 2; // 16 MiB each
    const size_t need = sz_xh + sz_wqkv + sz_wprj + sz_qkv + sz_t*3 + sz_xh;
    if (ws_size < need) return;

    char* ws = (char*)d_ws;
    size_t off = 0;
    auto alloc = [&](size_t bytes){ void* p = ws + off; off += (bytes + 255) & ~(size_t)255; return p; };
    u16* x_h     = (u16*)alloc(sz_xh);
    u16* wqkv_h  = (u16*)alloc(sz_wqkv);
    u16* wprj_h  = (u16*)alloc(sz_wprj);
    u16* qkv     = (u16*)alloc(sz_qkv);
    u16* qr      = (u16*)alloc(sz_t);
    u16* kr      = (u16*)alloc(sz_t);
    u16* vt      = (u16*)alloc(sz_t);
    u16* ob      = (u16*)alloc(sz_xh);
    u16* vt2     = qkv;   // qkv is dead after k_norm_rope; reuse for transposed V

    k_f2h<<<2048, 256, 0, stream>>>(x, x_h, MM * CC / 4);
    k_f2h<<<2048, 256, 0, stream>>>(w_qkv, wqkv_h, FF * CC / 4);
    k_f2h<<<1024, 256, 0, stream>>>(w_proj, wprj_h, CC * CC / 4);
    k_gemm_bt<1><<<dim3(FF / 128, MM / 128), 256, 0, stream>>>(
        x_h, wqkv_h, nullptr, qkv, nullptr, MM, FF, CC);
    k_norm_rope<<<MM, 256, 0, stream>>>(qkv, qw, kw, cosb, sinb, qr, kr, vt);
    k_vtrans<<<dim3(NN / 64, DD / 64, BB * HH), 256, 0, stream>>>(vt, vt2);
    k_attn5<<<512, 256, 0, stream>>>(qr, kr, vt2, ob);
    k_gemm_bt<0><<<dim3(CC / 128, MM / 128), 256, 0, stream>>>(
        ob, wprj_h, out, nullptr, b_proj, MM, CC, CC);
}

// Round 7
// 325.951 us; speedup vs baseline: 1.8438x; 1.0553x over previous
//
#include <hip/hip_runtime.h>
#include <stdint.h>

typedef unsigned short u16;
typedef unsigned int   u32;
typedef _Float16 f16_t;
typedef f16_t f16x8 __attribute__((ext_vector_type(8)));
typedef float  f32x4  __attribute__((ext_vector_type(4)));

#define BB 2
#define NN 2048
#define CC 2048
#define HH 16
#define DD 128
#define FF 6144
#define MM 4096

__device__ __forceinline__ u16 f2h(float f){
    f16_t h = (f16_t)f;
    return __builtin_bit_cast(u16, h);
}
__device__ __forceinline__ float h2f(u16 b){
    return (float)__builtin_bit_cast(f16_t, b);
}
__device__ __forceinline__ f32x4 MFMA(f16x8 a, f16x8 b, f32x4 c){
    return __builtin_amdgcn_mfma_f32_16x16x32_f16(a, b, c, 0, 0, 0);
}
__device__ __forceinline__ void gld16(const void* g, void* l){
    __builtin_amdgcn_global_load_lds(
        (const __attribute__((address_space(1))) void*)(g),
        (__attribute__((address_space(3))) void*)(l), 16, 0, 0);
}

// ---------------- fp32 -> fp16 conversion ----------------
__global__ void k_f2h(const float* __restrict__ a, u16* __restrict__ o, int n4){
    int i = blockIdx.x * blockDim.x + threadIdx.x;
    int stride = gridDim.x * blockDim.x;
    for (; i < n4; i += stride){
        float4 v = ((const float4*)a)[i];
        ushort4 r; r.x = f2h(v.x); r.y = f2h(v.y); r.z = f2h(v.z); r.w = f2h(v.w);
        ((ushort4*)o)[i] = r;
    }
}

// ---------------- GEMM:  out[m][n] = sum_k A[m][k] * Bw[n][k]  (fp16 MFMA) ------
// Stage-ahead double buffer (attn5-proven T3-minimum): the top-of-loop barrier
// drains loads issued one FULL compute phase earlier, not just-issued ones.
// LDS XOR swizzle on both sides (global source col + ds_read col) -> 0 conflicts.
template<int OUTH>
__global__ __launch_bounds__(256) void k_gemm_bt(
    const u16* __restrict__ A, const u16* __restrict__ Bw,
    float* __restrict__ outf, u16* __restrict__ outb,
    const float* __restrict__ bias, int M, int N, int K)
{
    __shared__ u16 As[2][128 * 32];
    __shared__ u16 Bs[2][128 * 32];
    const int tid  = threadIdx.x;
    const int brow = blockIdx.y * 128;
    const int bcol = blockIdx.x * 128;
    const int w = tid >> 6, lane = tid & 63;
    const int wr = w >> 1, wc = w & 1;
    const int l15 = lane & 15, g = lane >> 4;
    const int sr  = tid >> 2;                               // staged row 0..63 (+64)
    const int scz = ((tid & 3) ^ ((tid >> 3) & 3)) * 8;     // swizzled source col-block
    const int gx  = (g ^ ((l15 >> 1) & 3)) * 8;             // swizzled read col offset

    f32x4 acc[4][4];
    #pragma unroll
    for (int i = 0; i < 4; i++)
        #pragma unroll
        for (int j = 0; j < 4; j++){
            f32x4 z = {0.f, 0.f, 0.f, 0.f};
            acc[i][j] = z;
        }

    auto stage = [&](int buf, int k0){
        gld16(&Bw[(size_t)(bcol + sr) * K + k0 + scz],      &Bs[buf][w * 512]);
        gld16(&Bw[(size_t)(bcol + sr + 64) * K + k0 + scz], &Bs[buf][2048 + w * 512]);
        gld16(&A [(size_t)(brow + sr) * K + k0 + scz],      &As[buf][w * 512]);
        gld16(&A [(size_t)(brow + sr + 64) * K + k0 + scz], &As[buf][2048 + w * 512]);
    };

    stage(0, 0);
    int cur = 0;
    for (int k0 = 0; k0 < K; k0 += 32){
        __syncthreads();                     // waits on loads issued LAST iter
        if (k0 + 32 < K) stage(cur ^ 1, k0 + 32);
        f16x8 fb[4];
        #pragma unroll
        for (int j = 0; j < 4; j++){
            int row = wc * 64 + j * 16 + l15;
            fb[j] = *(const f16x8*)&Bs[cur][row * 32 + gx];
        }
        #pragma unroll
        for (int i = 0; i < 4; i++){
            int row = wr * 64 + i * 16 + l15;
            f16x8 fa = *(const f16x8*)&As[cur][row * 32 + gx];
            #pragma unroll
            for (int j = 0; j < 4; j++) acc[i][j] = MFMA(fa, fb[j], acc[i][j]);
        }
        cur ^= 1;
    }

    #pragma unroll
    for (int i = 0; i < 4; i++){
        #pragma unroll
        for (int j = 0; j < 4; j++){
            int colg = bcol + wc * 64 + j * 16 + l15;
            #pragma unroll
            for (int r = 0; r < 4; r++){
                int rowg = brow + wr * 64 + i * 16 + 4 * g + r;
                float v = acc[i][j][r];
                if (OUTH) outb[(size_t)rowg * N + colg] = f2h(v);
                else      outf[(size_t)rowg * N + colg] = v + bias[colg];
            }
        }
    }
}

// ---------------- RMSNorm + RoPE + transpose to (B,H,N,D), fp16 ----------------
// q is pre-scaled by D^-0.5 * log2(e) so attention can exp2 directly.
__global__ __launch_bounds__(256) void k_norm_rope(
    const u16* __restrict__ qkv, const float* __restrict__ qw, const float* __restrict__ kw,
    const float* __restrict__ cosb, const float* __restrict__ sinb,
    u16* __restrict__ qout, u16* __restrict__ kout, u16* __restrict__ vout)
{
    const int m = blockIdx.x;           // 0..4095  (b*N + n)
    const int b = m >> 11;
    const int n = m & 2047;
    const int t = threadIdx.x;
    const size_t base = (size_t)m * FF;
    const int e0 = t * 8;
    const float SCL = 0.08838834764831845f * 1.4426950408889634f;

    float qv[8], kvv[8];
    uint4 qa = *(const uint4*)&qkv[base + e0];
    uint4 ka = *(const uint4*)&qkv[base + CC + e0];
    uint4 va = *(const uint4*)&qkv[base + 2 * CC + e0];
    {
        u32 aa[4] = {qa.x, qa.y, qa.z, qa.w};
        u32 bb[4] = {ka.x, ka.y, ka.z, ka.w};
        #pragma unroll
        for (int i = 0; i < 4; i++){
            qv[2*i]   = h2f((u16)(aa[i] & 0xffff));
            qv[2*i+1] = h2f((u16)(aa[i] >> 16));
            kvv[2*i]   = h2f((u16)(bb[i] & 0xffff));
            kvv[2*i+1] = h2f((u16)(bb[i] >> 16));
        }
    }
    float sq = 0.f, sk = 0.f;
    #pragma unroll
    for (int i = 0; i < 8; i++){ sq += qv[i]*qv[i]; sk += kvv[i]*kvv[i]; }
    #pragma unroll
    for (int o = 32; o > 0; o >>= 1){ sq += __shfl_xor(sq, o); sk += __shfl_xor(sk, o); }
    __shared__ float red[8];
    if ((t & 63) == 0){ red[(t >> 6)*2] = sq; red[(t >> 6)*2 + 1] = sk; }
    __syncthreads();
    sq = red[0] + red[2] + red[4] + red[6];
    sk = red[1] + red[3] + red[5] + red[7];
    const float rq = rsqrtf(sq * (1.f / 2048.f) + 1e-5f);
    const float rk = rsqrtf(sk * (1.f / 2048.f) + 1e-5f);

    const int h  = t >> 4;
    const int d0 = (t & 15) * 8;
    const float* cp = cosb + (size_t)n * DD + d0;
    const float* sp = sinb + (size_t)n * DD + d0;
    float qo[8], ko[8];
    #pragma unroll
    for (int j = 0; j < 8; j += 2){
        float c0 = cp[j], c1 = cp[j+1], s0 = sp[j], s1 = sp[j+1];
        float x0 = qv[j]   * rq * qw[e0 + j];
        float x1 = qv[j+1] * rq * qw[e0 + j + 1];
        qo[j]   = (x0 * c0 - x1 * s0) * SCL;
        qo[j+1] = (x1 * c1 + x0 * s1) * SCL;
        float y0 = kvv[j]   * rk * kw[e0 + j];
        float y1 = kvv[j+1] * rk * kw[e0 + j + 1];
        ko[j]   = y0 * c0 - y1 * s0;
        ko[j+1] = y1 * c1 + y0 * s1;
    }
    const size_t obase = ((size_t)(b * HH + h) * NN + n) * DD + d0;
    uint4 pq, pk;
    pq.x = (u32)f2h(qo[0]) | ((u32)f2h(qo[1]) << 16);
    pq.y = (u32)f2h(qo[2]) | ((u32)f2h(qo[3]) << 16);
    pq.z = (u32)f2h(qo[4]) | ((u32)f2h(qo[5]) << 16);
    pq.w = (u32)f2h(qo[6]) | ((u32)f2h(qo[7]) << 16);
    pk.x = (u32)f2h(ko[0]) | ((u32)f2h(ko[1]) << 16);
    pk.y = (u32)f2h(ko[2]) | ((u32)f2h(ko[3]) << 16);
    pk.z = (u32)f2h(ko[4]) | ((u32)f2h(ko[5]) << 16);
    pk.w = (u32)f2h(ko[6]) | ((u32)f2h(ko[7]) << 16);
    *(uint4*)&qout[obase] = pq;
    *(uint4*)&kout[obase] = pk;
    *(uint4*)&vout[obase] = va;   // v: pass-through (already fp16)
}

// ---------------- V transpose: (BH, N, D) -> (BH, D, N) ----------------
__global__ __launch_bounds__(256) void k_vtrans(const u16* __restrict__ V, u16* __restrict__ Vt){
    __shared__ u16 t[64 * 66];
    const int bh = blockIdx.z;
    const int n0 = blockIdx.x * 64, d0 = blockIdx.y * 64;
    const int tid = threadIdx.x;
    const int q = tid & 7, p = tid >> 3;
    #pragma unroll
    for (int it = 0; it < 2; it++){
        int r = p + it * 32;
        const u16* src = V + ((size_t)bh * NN + n0 + r) * DD + d0 + q * 8;
        uint4 v = *(const uint4*)src;
        u32* dst = (u32*)&t[r * 66 + q * 8];
        dst[0] = v.x; dst[1] = v.y; dst[2] = v.z; dst[3] = v.w;
    }
    __syncthreads();
    #pragma unroll
    for (int it = 0; it < 2; it++){
        int rd = p + it * 32;
        u16 o[8];
        #pragma unroll
        for (int j = 0; j < 8; j++) o[j] = t[(q * 8 + j) * 66 + rd];
        *(uint4*)(Vt + ((size_t)bh * DD + d0 + rd) * NN + n0 + q * 8) = *(uint4*)o;
    }
}

// ---------------- attention v5: LDS-staged K/V (fragment-order), 2-phase dbuf ----
__global__ __launch_bounds__(256, 2) void k_attn5(
    const u16* __restrict__ Q, const u16* __restrict__ Kt, const u16* __restrict__ Vt2,
    u16* __restrict__ O)
{
    __shared__ u16 Kbuf[2][8192];   // 16 slots: s = hh*8 + t*4 + c
    __shared__ u16 Vbuf[2][8192];   // 16 slots: s = hh*8 + tb
    const int tid = threadIdx.x;
    const int w = tid >> 6, lane = tid & 63;
    const int l15 = lane & 15, g = lane >> 4;
    const int flat = blockIdx.x;
    const int lid  = (flat & 7) * 64 + (flat >> 3);   // bijective XCD swizzle (512 blocks)
    const int qb = lid & 15;
    const int h  = (lid >> 4) & 15;
    const int b  = lid >> 8;
    const size_t hb  = (size_t)(b * HH + h) * NN * DD;  // Q, K: (N,D)
    const size_t hbT = (size_t)(b * HH + h) * DD * NN;  // Vt2: (D,N)
    const int qbase = qb * 128 + w * 32;
    const int mperm = 8 * (l15 >> 2) + (l15 & 3);

    f16x8 qf[2][4];
    #pragma unroll
    for (int u = 0; u < 2; u++){
        const u16* qrow = Q + hb + (size_t)(qbase + u * 16 + l15) * DD;
        #pragma unroll
        for (int c = 0; c < 4; c++)
            qf[u][c] = *(const f16x8*)(qrow + c * 32 + 8 * g);
    }

    f32x4 oacc[2][8];
    #pragma unroll
    for (int u = 0; u < 2; u++)
        #pragma unroll
        for (int tb = 0; tb < 8; tb++){ f32x4 z = {0.f,0.f,0.f,0.f}; oacc[u][tb] = z; }
    float lsum0 = 0.f, lsum1 = 0.f;

    auto stage = [&](int buf, int kv0){
        #pragma unroll
        for (int it = 0; it < 8; it++){
            int s = it * 4 + w;                 // 0..31, each slot once
            if (s < 16){
                int hh = s >> 3, t = (s >> 2) & 1, c = s & 3;
                gld16(&Kt[hb + (size_t)(kv0 + 32 * hh + 4 * t + mperm) * DD + 32 * c + 8 * g],
                      &Kbuf[buf][s * 512]);
            } else {
                int s2 = s - 16;
                int hh = s2 >> 3, tb = s2 & 7;
                gld16(&Vt2[hbT + (size_t)(tb * 16 + l15) * NN + kv0 + 32 * hh + 8 * g],
                      &Vbuf[buf][s2 * 512]);
            }
        }
    };

    int cur = 0;
    stage(0, 0);
    for (int kv0 = 0; kv0 < NN; kv0 += 64){
        __syncthreads();                         // buf[cur] staged; prev reads done
        if (kv0 + 64 < NN) stage(cur ^ 1, kv0 + 64);
        const u16* kb = &Kbuf[cur][0] + lane * 8;
        const u16* vb = &Vbuf[cur][0] + lane * 8;
        #pragma unroll
        for (int hh = 0; hh < 2; hh++){
            f32x4 st00 = {0,0,0,0}, st01 = {0,0,0,0}, st10 = {0,0,0,0}, st11 = {0,0,0,0};
            #pragma unroll
            for (int c = 0; c < 4; c++){
                f16x8 kf0 = *(const f16x8*)(kb + (hh * 8 + c) * 512);
                f16x8 kf1 = *(const f16x8*)(kb + (hh * 8 + 4 + c) * 512);
                st00 = MFMA(kf0, qf[0][c], st00);
                st01 = MFMA(kf0, qf[1][c], st01);
                st10 = MFMA(kf1, qf[0][c], st10);
                st11 = MFMA(kf1, qf[1][c], st11);
            }
            f16x8 pf0, pf1;
            #pragma unroll
            for (int r = 0; r < 4; r++){
                float e00 = exp2f(st00[r]), e10 = exp2f(st10[r]);
                float e01 = exp2f(st01[r]), e11 = exp2f(st11[r]);
                lsum0 += e00 + e10;
                lsum1 += e01 + e11;
                pf0[r] = (f16_t)e00; pf0[r + 4] = (f16_t)e10;
                pf1[r] = (f16_t)e01; pf1[r + 4] = (f16_t)e11;
            }
            #pragma unroll
            for (int tb = 0; tb < 8; tb++){
                f16x8 vf = *(const f16x8*)(vb + (hh * 8 + tb) * 512);
                oacc[0][tb] = MFMA(pf0, vf, oacc[0][tb]);
                oacc[1][tb] = MFMA(pf1, vf, oacc[1][tb]);
            }
        }
        cur ^= 1;
    }

    lsum0 += __shfl_xor(lsum0, 16); lsum0 += __shfl_xor(lsum0, 32);
    lsum1 += __shfl_xor(lsum1, 16); lsum1 += __shfl_xor(lsum1, 32);
    float linv0 = 1.f / lsum0, linv1 = 1.f / lsum1;
    float li0[4], li1[4];
    #pragma unroll
    for (int r = 0; r < 4; r++){
        li0[r] = __shfl(linv0, 4 * g + r);
        li1[r] = __shfl(linv1, 4 * g + r);
    }

    #pragma unroll
    for (int tb = 0; tb < 8; tb++){
        #pragma unroll
        for (int r = 0; r < 4; r++){
            int q0 = qbase + 4 * g + r;
            O[(size_t)(b * NN + q0) * CC + h * DD + tb * 16 + l15] = f2h(oacc[0][tb][r] * li0[r]);
            int q1 = qbase + 16 + 4 * g + r;
            O[(size_t)(b * NN + q1) * CC + h * DD + tb * 16 + l15] = f2h(oacc[1][tb][r] * li1[r]);
        }
    }
}

// ---------------- launch ----------------
extern "C" void kernel_launch(void* const* d_in, const int* in_sizes, int n_in,
                              void* d_out, int out_size, void* d_ws, size_t ws_size,
                              hipStream_t stream) {
    const float* x      = (const float*)d_in[0];
    const float* w_qkv  = (const float*)d_in[1];
    const float* qw     = (const float*)d_in[2];
    const float* kw     = (const float*)d_in[3];
    const float* cosb   = (const float*)d_in[4];
    const float* sinb   = (const float*)d_in[5];
    const float* w_proj = (const float*)d_in[6];
    const float* b_proj = (const float*)d_in[7];
    float* out = (float*)d_out;

    const size_t sz_xh   = (size_t)MM * CC * 2;        // 16 MiB
    const size_t sz_wqkv = (size_t)FF * CC * 2;        // 24 MiB
    const size_t sz_wprj = (size_t)CC * CC * 2;        // 8 MiB
    const size_t sz_qkv  = (size_t)MM * FF * 2;        // 48 MiB
    const size_t sz_t    = (size_t)BB * HH * NN * DD * 2; // 16 MiB each
    const size_t need = sz_xh + sz_wqkv + sz_wprj + sz_qkv + sz_t*3 + sz_xh;
    if (ws_size < need) return;

    char* ws = (char*)d_ws;
    size_t off = 0;
    auto alloc = [&](size_t bytes){ void* p = ws + off; off += (bytes + 255) & ~(size_t)255; return p; };
    u16* x_h     = (u16*)alloc(sz_xh);
    u16* wqkv_h  = (u16*)alloc(sz_wqkv);
    u16* wprj_h  = (u16*)alloc(sz_wprj);
    u16* qkv     = (u16*)alloc(sz_qkv);
    u16* qr      = (u16*)alloc(sz_t);
    u16* kr      = (u16*)alloc(sz_t);
    u16* vt      = (u16*)alloc(sz_t);
    u16* ob      = (u16*)alloc(sz_xh);
    u16* vt2     = qkv;   // qkv is dead after k_norm_rope; reuse for transposed V

    k_f2h<<<2048, 256, 0, stream>>>(x, x_h, MM * CC / 4);
    k_f2h<<<2048, 256, 0, stream>>>(w_qkv, wqkv_h, FF * CC / 4);
    k_f2h<<<1024, 256, 0, stream>>>(w_proj, wprj_h, CC * CC / 4);
    k_gemm_bt<1><<<dim3(FF / 128, MM / 128), 256, 0, stream>>>(
        x_h, wqkv_h, nullptr, qkv, nullptr, MM, FF, CC);
    k_norm_rope<<<MM, 256, 0, stream>>>(qkv, qw, kw, cosb, sinb, qr, kr, vt);
    k_vtrans<<<dim3(NN / 64, DD / 64, BB * HH), 256, 0, stream>>>(vt, vt2);
    k_attn5<<<512, 256, 0, stream>>>(qr, kr, vt2, ob);
    k_gemm_bt<0><<<dim3(CC / 128, MM / 128), 256, 0, stream>>>(
        ob, wprj_h, out, nullptr, b_proj, MM, CC, CC);
}

// Round 8
// 318.577 us; speedup vs baseline: 1.8865x; 1.0231x over previous
//
#include <hip/hip_runtime.h>
#include <stdint.h>

typedef unsigned short u16;
typedef unsigned int   u32;
typedef _Float16 f16_t;
typedef f16_t f16x8 __attribute__((ext_vector_type(8)));
typedef float  f32x4  __attribute__((ext_vector_type(4)));

#define BB 2
#define NN 2048
#define CC 2048
#define HH 16
#define DD 128
#define FF 6144
#define MM 4096

__device__ __forceinline__ u16 f2h(float f){
    f16_t h = (f16_t)f;
    return __builtin_bit_cast(u16, h);
}
__device__ __forceinline__ float h2f(u16 b){
    return (float)__builtin_bit_cast(f16_t, b);
}
__device__ __forceinline__ f32x4 MFMA(f16x8 a, f16x8 b, f32x4 c){
    return __builtin_amdgcn_mfma_f32_16x16x32_f16(a, b, c, 0, 0, 0);
}
__device__ __forceinline__ void gld16(const void* g, void* l){
    __builtin_amdgcn_global_load_lds(
        (const __attribute__((address_space(1))) void*)(g),
        (__attribute__((address_space(3))) void*)(l), 16, 0, 0);
}

// ---------------- fp32 -> fp16 conversion ----------------
__global__ void k_f2h(const float* __restrict__ a, u16* __restrict__ o, int n4){
    int i = blockIdx.x * blockDim.x + threadIdx.x;
    int stride = gridDim.x * blockDim.x;
    for (; i < n4; i += stride){
        float4 v = ((const float4*)a)[i];
        ushort4 r; r.x = f2h(v.x); r.y = f2h(v.y); r.z = f2h(v.z); r.w = f2h(v.w);
        ((ushort4*)o)[i] = r;
    }
}

// ---------------- GEMM:  out[m][n] = sum_k A[m][k] * Bw[n][k]  (fp16 MFMA) ------
// Counted-vmcnt triple buffer (T4): raw barriers + s_waitcnt vmcnt(8).
// Schedule per iter i (compute buf c = i%3 holding K_i, staged 2 iters ago):
//   barrier A  : all waves done READING buf[(i+2)%3] (= buf[(i-1)%3], read iter i-1)
//   stage K_{i+2} -> buf[(i+2)%3]   (issue-after-A => lands after readers passed)
//   vmcnt(8)   : own K_i loads (oldest 4 of 12) landed   [tail: 4 / 0]
//   barrier B  : everyone's K_i loads landed
//   ds_read buf[c] + 16 MFMA
// LDS XOR swizzle on both sides (global source col + ds_read col) -> 0 conflicts.
template<int OUTH>
__global__ __launch_bounds__(256) void k_gemm_bt(
    const u16* __restrict__ A, const u16* __restrict__ Bw,
    float* __restrict__ outf, u16* __restrict__ outb,
    const float* __restrict__ bias, int M, int N, int K)
{
    __shared__ u16 As[3][128 * 32];
    __shared__ u16 Bs[3][128 * 32];
    const int tid  = threadIdx.x;
    const int brow = blockIdx.y * 128;
    const int bcol = blockIdx.x * 128;
    const int w = tid >> 6, lane = tid & 63;
    const int wr = w >> 1, wc = w & 1;
    const int l15 = lane & 15, g = lane >> 4;
    const int sr  = tid >> 2;                               // staged row 0..63 (+64)
    const int scz = ((tid & 3) ^ ((tid >> 3) & 3)) * 8;     // swizzled source col-block
    const int gx  = (g ^ ((l15 >> 1) & 3)) * 8;             // swizzled read col offset

    f32x4 acc[4][4];
    #pragma unroll
    for (int i = 0; i < 4; i++)
        #pragma unroll
        for (int j = 0; j < 4; j++){
            f32x4 z = {0.f, 0.f, 0.f, 0.f};
            acc[i][j] = z;
        }

    auto stage = [&](int buf, int k0){
        gld16(&Bw[(size_t)(bcol + sr) * K + k0 + scz],      &Bs[buf][w * 512]);
        gld16(&Bw[(size_t)(bcol + sr + 64) * K + k0 + scz], &Bs[buf][2048 + w * 512]);
        gld16(&A [(size_t)(brow + sr) * K + k0 + scz],      &As[buf][w * 512]);
        gld16(&A [(size_t)(brow + sr + 64) * K + k0 + scz], &As[buf][2048 + w * 512]);
    };

    stage(0, 0);
    stage(1, 32);
    int c = 0;
    for (int k0 = 0; k0 < K; k0 += 32){
        __builtin_amdgcn_sched_barrier(0);
        __builtin_amdgcn_s_barrier();          // A
        __builtin_amdgcn_sched_barrier(0);
        int ct = c + 2; if (ct >= 3) ct -= 3;
        if (k0 + 64 < K){
            stage(ct, k0 + 64);
            asm volatile("s_waitcnt vmcnt(8)" ::: "memory");
        } else if (k0 + 32 < K){
            asm volatile("s_waitcnt vmcnt(4)" ::: "memory");
        } else {
            asm volatile("s_waitcnt vmcnt(0)" ::: "memory");
        }
        __builtin_amdgcn_sched_barrier(0);
        __builtin_amdgcn_s_barrier();          // B
        __builtin_amdgcn_sched_barrier(0);
        f16x8 fb[4];
        #pragma unroll
        for (int j = 0; j < 4; j++){
            int row = wc * 64 + j * 16 + l15;
            fb[j] = *(const f16x8*)&Bs[c][row * 32 + gx];
        }
        #pragma unroll
        for (int i = 0; i < 4; i++){
            int row = wr * 64 + i * 16 + l15;
            f16x8 fa = *(const f16x8*)&As[c][row * 32 + gx];
            #pragma unroll
            for (int j = 0; j < 4; j++) acc[i][j] = MFMA(fa, fb[j], acc[i][j]);
        }
        c = (c + 1 == 3) ? 0 : c + 1;
    }

    #pragma unroll
    for (int i = 0; i < 4; i++){
        #pragma unroll
        for (int j = 0; j < 4; j++){
            int colg = bcol + wc * 64 + j * 16 + l15;
            #pragma unroll
            for (int r = 0; r < 4; r++){
                int rowg = brow + wr * 64 + i * 16 + 4 * g + r;
                float v = acc[i][j][r];
                if (OUTH) outb[(size_t)rowg * N + colg] = f2h(v);
                else      outf[(size_t)rowg * N + colg] = v + bias[colg];
            }
        }
    }
}

// ---------------- RMSNorm + RoPE (q,k only) -> (B,H,N,D), fp16 ----------------
// q is pre-scaled by D^-0.5 * log2(e) so attention can exp2 directly.
// V is NOT touched here (k_vtrans reads it straight out of qkv).
__global__ __launch_bounds__(256) void k_norm_rope(
    const u16* __restrict__ qkv, const float* __restrict__ qw, const float* __restrict__ kw,
    const float* __restrict__ cosb, const float* __restrict__ sinb,
    u16* __restrict__ qout, u16* __restrict__ kout)
{
    const int m = blockIdx.x;           // 0..4095  (b*N + n)
    const int b = m >> 11;
    const int n = m & 2047;
    const int t = threadIdx.x;
    const size_t base = (size_t)m * FF;
    const int e0 = t * 8;
    const float SCL = 0.08838834764831845f * 1.4426950408889634f;

    float qv[8], kvv[8];
    uint4 qa = *(const uint4*)&qkv[base + e0];
    uint4 ka = *(const uint4*)&qkv[base + CC + e0];
    {
        u32 aa[4] = {qa.x, qa.y, qa.z, qa.w};
        u32 bb[4] = {ka.x, ka.y, ka.z, ka.w};
        #pragma unroll
        for (int i = 0; i < 4; i++){
            qv[2*i]   = h2f((u16)(aa[i] & 0xffff));
            qv[2*i+1] = h2f((u16)(aa[i] >> 16));
            kvv[2*i]   = h2f((u16)(bb[i] & 0xffff));
            kvv[2*i+1] = h2f((u16)(bb[i] >> 16));
        }
    }
    float sq = 0.f, sk = 0.f;
    #pragma unroll
    for (int i = 0; i < 8; i++){ sq += qv[i]*qv[i]; sk += kvv[i]*kvv[i]; }
    #pragma unroll
    for (int o = 32; o > 0; o >>= 1){ sq += __shfl_xor(sq, o); sk += __shfl_xor(sk, o); }
    __shared__ float red[8];
    if ((t & 63) == 0){ red[(t >> 6)*2] = sq; red[(t >> 6)*2 + 1] = sk; }
    __syncthreads();
    sq = red[0] + red[2] + red[4] + red[6];
    sk = red[1] + red[3] + red[5] + red[7];
    const float rq = rsqrtf(sq * (1.f / 2048.f) + 1e-5f);
    const float rk = rsqrtf(sk * (1.f / 2048.f) + 1e-5f);

    const int h  = t >> 4;
    const int d0 = (t & 15) * 8;
    const float* cp = cosb + (size_t)n * DD + d0;
    const float* sp = sinb + (size_t)n * DD + d0;
    float qo[8], ko[8];
    #pragma unroll
    for (int j = 0; j < 8; j += 2){
        float c0 = cp[j], c1 = cp[j+1], s0 = sp[j], s1 = sp[j+1];
        float x0 = qv[j]   * rq * qw[e0 + j];
        float x1 = qv[j+1] * rq * qw[e0 + j + 1];
        qo[j]   = (x0 * c0 - x1 * s0) * SCL;
        qo[j+1] = (x1 * c1 + x0 * s1) * SCL;
        float y0 = kvv[j]   * rk * kw[e0 + j];
        float y1 = kvv[j+1] * rk * kw[e0 + j + 1];
        ko[j]   = y0 * c0 - y1 * s0;
        ko[j+1] = y1 * c1 + y0 * s1;
    }
    const size_t obase = ((size_t)(b * HH + h) * NN + n) * DD + d0;
    uint4 pq, pk;
    pq.x = (u32)f2h(qo[0]) | ((u32)f2h(qo[1]) << 16);
    pq.y = (u32)f2h(qo[2]) | ((u32)f2h(qo[3]) << 16);
    pq.z = (u32)f2h(qo[4]) | ((u32)f2h(qo[5]) << 16);
    pq.w = (u32)f2h(qo[6]) | ((u32)f2h(qo[7]) << 16);
    pk.x = (u32)f2h(ko[0]) | ((u32)f2h(ko[1]) << 16);
    pk.y = (u32)f2h(ko[2]) | ((u32)f2h(ko[3]) << 16);
    pk.z = (u32)f2h(ko[4]) | ((u32)f2h(ko[5]) << 16);
    pk.w = (u32)f2h(ko[6]) | ((u32)f2h(ko[7]) << 16);
    *(uint4*)&qout[obase] = pq;
    *(uint4*)&kout[obase] = pk;
}

// ---------------- V transpose: qkv v-slice (B,N,H,D) -> (BH, D, N) ----------------
__global__ __launch_bounds__(256) void k_vtrans(const u16* __restrict__ qkv, u16* __restrict__ Vt){
    __shared__ u16 t[64 * 66];
    const int bh = blockIdx.z;
    const int b = bh >> 4, h = bh & 15;
    const int n0 = blockIdx.x * 64, d0 = blockIdx.y * 64;
    const int tid = threadIdx.x;
    const int q = tid & 7, p = tid >> 3;
    #pragma unroll
    for (int it = 0; it < 2; it++){
        int r = p + it * 32;
        const u16* src = qkv + (size_t)(b * NN + n0 + r) * FF + 2 * CC + h * DD + d0 + q * 8;
        uint4 v = *(const uint4*)src;
        u32* dst = (u32*)&t[r * 66 + q * 8];
        dst[0] = v.x; dst[1] = v.y; dst[2] = v.z; dst[3] = v.w;
    }
    __syncthreads();
    #pragma unroll
    for (int it = 0; it < 2; it++){
        int rd = p + it * 32;
        u16 o[8];
        #pragma unroll
        for (int j = 0; j < 8; j++) o[j] = t[(q * 8 + j) * 66 + rd];
        *(uint4*)(Vt + ((size_t)bh * DD + d0 + rd) * NN + n0 + q * 8) = *(uint4*)o;
    }
}

// ---------------- attention v5: LDS-staged K/V (fragment-order), 2-phase dbuf ----
__global__ __launch_bounds__(256, 2) void k_attn5(
    const u16* __restrict__ Q, const u16* __restrict__ Kt, const u16* __restrict__ Vt2,
    u16* __restrict__ O)
{
    __shared__ u16 Kbuf[2][8192];   // 16 slots: s = hh*8 + t*4 + c
    __shared__ u16 Vbuf[2][8192];   // 16 slots: s = hh*8 + tb
    const int tid = threadIdx.x;
    const int w = tid >> 6, lane = tid & 63;
    const int l15 = lane & 15, g = lane >> 4;
    const int flat = blockIdx.x;
    const int lid  = (flat & 7) * 64 + (flat >> 3);   // bijective XCD swizzle (512 blocks)
    const int qb = lid & 15;
    const int h  = (lid >> 4) & 15;
    const int b  = lid >> 8;
    const size_t hb  = (size_t)(b * HH + h) * NN * DD;  // Q, K: (N,D)
    const size_t hbT = (size_t)(b * HH + h) * DD * NN;  // Vt2: (D,N)
    const int qbase = qb * 128 + w * 32;
    const int mperm = 8 * (l15 >> 2) + (l15 & 3);

    f16x8 qf[2][4];
    #pragma unroll
    for (int u = 0; u < 2; u++){
        const u16* qrow = Q + hb + (size_t)(qbase + u * 16 + l15) * DD;
        #pragma unroll
        for (int c = 0; c < 4; c++)
            qf[u][c] = *(const f16x8*)(qrow + c * 32 + 8 * g);
    }

    f32x4 oacc[2][8];
    #pragma unroll
    for (int u = 0; u < 2; u++)
        #pragma unroll
        for (int tb = 0; tb < 8; tb++){ f32x4 z = {0.f,0.f,0.f,0.f}; oacc[u][tb] = z; }
    float lsum0 = 0.f, lsum1 = 0.f;

    auto stage = [&](int buf, int kv0){
        #pragma unroll
        for (int it = 0; it < 8; it++){
            int s = it * 4 + w;                 // 0..31, each slot once
            if (s < 16){
                int hh = s >> 3, t = (s >> 2) & 1, c = s & 3;
                gld16(&Kt[hb + (size_t)(kv0 + 32 * hh + 4 * t + mperm) * DD + 32 * c + 8 * g],
                      &Kbuf[buf][s * 512]);
            } else {
                int s2 = s - 16;
                int hh = s2 >> 3, tb = s2 & 7;
                gld16(&Vt2[hbT + (size_t)(tb * 16 + l15) * NN + kv0 + 32 * hh + 8 * g],
                      &Vbuf[buf][s2 * 512]);
            }
        }
    };

    int cur = 0;
    stage(0, 0);
    for (int kv0 = 0; kv0 < NN; kv0 += 64){
        __syncthreads();                         // buf[cur] staged; prev reads done
        if (kv0 + 64 < NN) stage(cur ^ 1, kv0 + 64);
        const u16* kb = &Kbuf[cur][0] + lane * 8;
        const u16* vb = &Vbuf[cur][0] + lane * 8;
        #pragma unroll
        for (int hh = 0; hh < 2; hh++){
            f32x4 st00 = {0,0,0,0}, st01 = {0,0,0,0}, st10 = {0,0,0,0}, st11 = {0,0,0,0};
            __builtin_amdgcn_s_setprio(1);
            #pragma unroll
            for (int c = 0; c < 4; c++){
                f16x8 kf0 = *(const f16x8*)(kb + (hh * 8 + c) * 512);
                f16x8 kf1 = *(const f16x8*)(kb + (hh * 8 + 4 + c) * 512);
                st00 = MFMA(kf0, qf[0][c], st00);
                st01 = MFMA(kf0, qf[1][c], st01);
                st10 = MFMA(kf1, qf[0][c], st10);
                st11 = MFMA(kf1, qf[1][c], st11);
            }
            __builtin_amdgcn_s_setprio(0);
            f16x8 pf0, pf1;
            #pragma unroll
            for (int r = 0; r < 4; r++){
                float e00 = exp2f(st00[r]), e10 = exp2f(st10[r]);
                float e01 = exp2f(st01[r]), e11 = exp2f(st11[r]);
                lsum0 += e00 + e10;
                lsum1 += e01 + e11;
                pf0[r] = (f16_t)e00; pf0[r + 4] = (f16_t)e10;
                pf1[r] = (f16_t)e01; pf1[r + 4] = (f16_t)e11;
            }
            __builtin_amdgcn_s_setprio(1);
            #pragma unroll
            for (int tb = 0; tb < 8; tb++){
                f16x8 vf = *(const f16x8*)(vb + (hh * 8 + tb) * 512);
                oacc[0][tb] = MFMA(pf0, vf, oacc[0][tb]);
                oacc[1][tb] = MFMA(pf1, vf, oacc[1][tb]);
            }
            __builtin_amdgcn_s_setprio(0);
        }
        cur ^= 1;
    }

    lsum0 += __shfl_xor(lsum0, 16); lsum0 += __shfl_xor(lsum0, 32);
    lsum1 += __shfl_xor(lsum1, 16); lsum1 += __shfl_xor(lsum1, 32);
    float linv0 = 1.f / lsum0, linv1 = 1.f / lsum1;
    float li0[4], li1[4];
    #pragma unroll
    for (int r = 0; r < 4; r++){
        li0[r] = __shfl(linv0, 4 * g + r);
        li1[r] = __shfl(linv1, 4 * g + r);
    }

    #pragma unroll
    for (int tb = 0; tb < 8; tb++){
        #pragma unroll
        for (int r = 0; r < 4; r++){
            int q0 = qbase + 4 * g + r;
            O[(size_t)(b * NN + q0) * CC + h * DD + tb * 16 + l15] = f2h(oacc[0][tb][r] * li0[r]);
            int q1 = qbase + 16 + 4 * g + r;
            O[(size_t)(b * NN + q1) * CC + h * DD + tb * 16 + l15] = f2h(oacc[1][tb][r] * li1[r]);
        }
    }
}

// ---------------- launch ----------------
extern "C" void kernel_launch(void* const* d_in, const int* in_sizes, int n_in,
                              void* d_out, int out_size, void* d_ws, size_t ws_size,
                              hipStream_t stream) {
    const float* x      = (const float*)d_in[0];
    const float* w_qkv  = (const float*)d_in[1];
    const float* qw     = (const float*)d_in[2];
    const float* kw     = (const float*)d_in[3];
    const float* cosb   = (const float*)d_in[4];
    const float* sinb   = (const float*)d_in[5];
    const float* w_proj = (const float*)d_in[6];
    const float* b_proj = (const float*)d_in[7];
    float* out = (float*)d_out;

    const size_t sz_xh   = (size_t)MM * CC * 2;        // 16 MiB
    const size_t sz_wqkv = (size_t)FF * CC * 2;        // 24 MiB
    const size_t sz_wprj = (size_t)CC * CC * 2;        // 8 MiB
    const size_t sz_qkv  = (size_t)MM * FF * 2;        // 48 MiB
    const size_t sz_t    = (size_t)BB * HH * NN * DD * 2; // 16 MiB each
    const size_t need = sz_xh + sz_wqkv + sz_wprj + sz_qkv + sz_t*3 + sz_xh;
    if (ws_size < need) return;

    char* ws = (char*)d_ws;
    size_t off = 0;
    auto alloc = [&](size_t bytes){ void* p = ws + off; off += (bytes + 255) & ~(size_t)255; return p; };
    u16* x_h     = (u16*)alloc(sz_xh);
    u16* wqkv_h  = (u16*)alloc(sz_wqkv);
    u16* wprj_h  = (u16*)alloc(sz_wprj);
    u16* qkv     = (u16*)alloc(sz_qkv);
    u16* qr      = (u16*)alloc(sz_t);
    u16* kr      = (u16*)alloc(sz_t);
    u16* vt2     = (u16*)alloc(sz_t);   // transposed V (B,H,D,N), read from qkv directly
    u16* ob      = (u16*)alloc(sz_xh);

    k_f2h<<<2048, 256, 0, stream>>>(x, x_h, MM * CC / 4);
    k_f2h<<<2048, 256, 0, stream>>>(w_qkv, wqkv_h, FF * CC / 4);
    k_f2h<<<1024, 256, 0, stream>>>(w_proj, wprj_h, CC * CC / 4);
    k_gemm_bt<1><<<dim3(FF / 128, MM / 128), 256, 0, stream>>>(
        x_h, wqkv_h, nullptr, qkv, nullptr, MM, FF, CC);
    k_norm_rope<<<MM, 256, 0, stream>>>(qkv, qw, kw, cosb, sinb, qr, kr);
    k_vtrans<<<dim3(NN / 64, DD / 64, BB * HH), 256, 0, stream>>>(qkv, vt2);
    k_attn5<<<512, 256, 0, stream>>>(qr, kr, vt2, ob);
    k_gemm_bt<0><<<dim3(CC / 128, MM / 128), 256, 0, stream>>>(
        ob, wprj_h, out, nullptr, b_proj, MM, CC, CC);
}